// Round 1
// baseline (6260.563 us; speedup 1.0000x reference)
//
#include <hip/hip_runtime.h>

// ---------------- problem dims ----------------
// B=1, S=1024, C=2048, H=32, D=64, HKV=8, R=16, FF=5632, Q_BIT=4 (qmax=7)

// ---------------- ws layout (float offsets) ----------------
#define WS_XN1   0L
#define WS_Q     2097152L
#define WS_KB    4194304L
#define WS_VB    4718592L
#define WS_OB    5242880L
#define WS_XMED  7340032L
#define WS_XN2   9437184L
#define WS_PROBS 11534336L
#define WS_GATE  (WS_PROBS)
#define WS_UP    (WS_PROBS + 5767168L)
#define WS_HAD   (WS_PROBS + 11534336L)
#define WS_SMALL 45088768L
#define CM_X     (WS_SMALL + 0L)
#define CM_XN1   (WS_SMALL + 2048L)
#define CM_Qb    (WS_SMALL + 4096L)
#define CM_Kb    (WS_SMALL + 4160L)
#define CM_Vb    (WS_SMALL + 4224L)
#define CM_Ob    (WS_SMALL + 4288L)
#define CM_XM    (WS_SMALL + 6336L)
#define CM_XN2b  (WS_SMALL + 8384L)
#define CM_GATE  (WS_SMALL + 10432L)
#define CM_FN    (WS_SMALL + 16064L)
#define CM_UPb   (WS_SMALL + 21696L)
#define CM_HAD   (WS_SMALL + 27328L)
#define CM_TOTAL 32960
#define WS_XA    (WS_SMALL + 32960L)
#define WS_IDX   (WS_XA + 16384L)
#define WS_HIST  (WS_IDX + 64L)
#define WS_SEL   (WS_HIST + 4096L)
#define WS_RES   (WS_SEL + 8L)

// ---------------- out layout (float offsets) ----------------
#define O_XOUT  0L
#define O_XIDX  2097152L
#define O_XSC   2097172L
#define O_XN1S  2099220L
#define O_QS    2101268L
#define O_KS    2101332L
#define O_VS    2101396L
#define O_ATHR  2101460L
#define O_OS    2101461L
#define O_XMIDX 2103509L
#define O_XMS   2103529L
#define O_XN2S  2105577L
#define O_GATES 2107625L
#define O_UPS   2113257L
#define O_FNS   2118889L
#define O_HADS  2124521L

#define FMA16(a4,b4,acc) do { \
  acc[0][0] += a4.x*b4.x; acc[0][1] += a4.x*b4.y; acc[0][2] += a4.x*b4.z; acc[0][3] += a4.x*b4.w; \
  acc[1][0] += a4.y*b4.x; acc[1][1] += a4.y*b4.y; acc[1][2] += a4.y*b4.z; acc[1][3] += a4.y*b4.w; \
  acc[2][0] += a4.z*b4.x; acc[2][1] += a4.z*b4.y; acc[2][2] += a4.z*b4.z; acc[2][3] += a4.z*b4.w; \
  acc[3][0] += a4.w*b4.x; acc[3][1] += a4.w*b4.y; acc[3][2] += a4.w*b4.z; acc[3][3] += a4.w*b4.w; \
} while (0)

// ---------------- small utility kernels ----------------
__global__ void zero_kernel(unsigned* __restrict__ p, int n) {
    int i = blockIdx.x * 256 + threadIdx.x;
    if (i < n) p[i] = 0u;
}

__global__ __launch_bounds__(256) void rmsnorm_kernel(const float* __restrict__ x,
                                                      const float* __restrict__ w,
                                                      float* __restrict__ out) {
    const int row = blockIdx.x;
    const int tid = threadIdx.x;
    const float* xr = x + row * 2048;
    float s = 0.f;
    for (int i = tid; i < 2048; i += 256) { float v = xr[i]; s += v * v; }
    __shared__ float red[256];
    red[tid] = s; __syncthreads();
    for (int off = 128; off; off >>= 1) { if (tid < off) red[tid] += red[tid + off]; __syncthreads(); }
    const float rstd = 1.0f / sqrtf(red[0] / 2048.0f + 1e-5f);
    float* orow = out + row * 2048;
    for (int i = tid; i < 2048; i += 256) orow[i] = xr[i] * rstd * w[i];
}

// per-column abs-max (mode 1: abs of silu) via atomicMax on non-negative float bits
__global__ void colabsmax_kernel(const float* __restrict__ in, int M, int N,
                                 unsigned* __restrict__ outb, int mode) {
    const int c = blockIdx.x * 256 + threadIdx.x;
    if (c >= N) return;
    float loc = 0.f;
    for (int r = blockIdx.y; r < M; r += gridDim.y) {
        float v = in[(long)r * N + c];
        if (mode) v = v / (1.f + expf(-v));
        loc = fmaxf(loc, fabsf(v));
    }
    atomicMax(outb + c, __float_as_uint(loc));
}

__global__ void scale_fin_kernel(const unsigned* __restrict__ bits, float* __restrict__ out, int n) {
    int i = blockIdx.x * 256 + threadIdx.x;
    if (i < n) out[i] = __uint_as_float(bits[i]) / 7.0f + 1e-8f;
}

__global__ __launch_bounds__(256) void topk20_kernel(const unsigned* __restrict__ cmaxbits,
                                                     float* __restrict__ out_idx_f,
                                                     int* __restrict__ out_idx_i) {
    __shared__ float vals[2048];
    __shared__ float rv[256];
    __shared__ int   ri[256];
    const int tid = threadIdx.x;
    for (int i = tid; i < 2048; i += 256) vals[i] = __uint_as_float(cmaxbits[i]);
    __syncthreads();
    for (int t = 0; t < 20; t++) {
        float bv = -1.f; int bi = 1 << 30;
        for (int i = tid; i < 2048; i += 256) {
            float v = vals[i];
            if (v > bv) { bv = v; bi = i; }
        }
        rv[tid] = bv; ri[tid] = bi; __syncthreads();
        for (int off = 128; off; off >>= 1) {
            if (tid < off) {
                float v2 = rv[tid + off]; int i2 = ri[tid + off];
                if (v2 > rv[tid] || (v2 == rv[tid] && i2 < ri[tid])) { rv[tid] = v2; ri[tid] = i2; }
            }
            __syncthreads();
        }
        if (tid == 0) { out_idx_f[t] = (float)ri[0]; out_idx_i[t] = ri[0]; vals[ri[0]] = -1.f; }
        __syncthreads();
    }
}

__global__ void packscale_kernel(const unsigned* __restrict__ cmaxbits,
                                 const int* __restrict__ idx, float* __restrict__ out, int n) {
    const int c = blockIdx.x * 256 + threadIdx.x;
    if (c >= n) return;
    bool outl = false;
    for (int t = 0; t < 20; t++) outl |= (idx[t] == c);
    const float m = __uint_as_float(cmaxbits[c]);
    out[c] = outl ? 1e-8f : (m / 7.0f + 1e-8f);
}

__global__ __launch_bounds__(256) void lora_xa_kernel(const float* __restrict__ A,
                                                      const float* __restrict__ la,
                                                      float* __restrict__ xa, int K) {
    const int m = blockIdx.x;
    const int tid = threadIdx.x;
    const int r = tid & 15, g = tid >> 4;
    float s = 0.f;
    const float* Am = A + (long)m * K;
    for (int k = g; k < K; k += 16) s += Am[k] * la[k * 16 + r];
    __shared__ float red[256];
    red[tid] = s; __syncthreads();
    for (int off = 128; off >= 16; off >>= 1) { if (tid < off) red[tid] += red[tid + off]; __syncthreads(); }
    if (tid < 16) xa[m * 16 + tid] = red[tid];
}

__global__ void rope_kernel(float* __restrict__ x, const float* __restrict__ cs,
                            const float* __restrict__ sn, int nh) {
    const int idx = blockIdx.x * 256 + threadIdx.x;
    const int tot = 1024 * nh * 32;
    if (idx >= tot) return;
    const int d = idx & 31;
    const int h = (idx >> 5) % nh;
    const int s = (idx >> 5) / nh;
    float* p = x + s * (nh * 64) + h * 64;
    const float x1 = p[d], x2 = p[d + 32];
    const float c1 = cs[s * 64 + d],      s1 = sn[s * 64 + d];
    const float c2 = cs[s * 64 + d + 32], s2 = sn[s * 64 + d + 32];
    p[d]      = x1 * c1 - x2 * s1;
    p[d + 32] = x2 * c2 + x1 * s2;
}

__global__ void hadamard_kernel(const float* __restrict__ gate, const float* __restrict__ up,
                                float* __restrict__ had, int n) {
    const int i = blockIdx.x * 256 + threadIdx.x;
    if (i < n) {
        const float g = gate[i];
        const float fn = g / (1.f + expf(-g));
        had[i] = up[i] * fn;
    }
}

// ---------------- GEMM: C = A * (Wi*sc)^T + b + xa*lb (+res) ----------------
__global__ __launch_bounds__(256) void gemm_qint_kernel(
    const float* __restrict__ A, const int* __restrict__ Wi,
    const float* __restrict__ sc, const float* __restrict__ bias,
    const float* __restrict__ xa, const float* __restrict__ lb,
    const float* __restrict__ res, float* __restrict__ Cout,
    int N, int K) {
    __shared__ __align__(16) float As[16][68];
    __shared__ __align__(16) float Ws[16][68];
    const int tid = threadIdx.x;
    const int tx = tid & 15, ty = tid >> 4;
    const int bn = blockIdx.x * 64, bm = blockIdx.y * 64;
    const int lr = tid >> 2, lq = tid & 3;
    const float* Ap = A + (long)(bm + lr) * K + lq * 4;
    const int*   Wp = Wi + (long)(bn + lr) * K + lq * 4;
    float acc[4][4] = {};
    for (int k0 = 0; k0 < K; k0 += 16) {
        const float4 av = *(const float4*)(Ap + k0);
        const int4   wv = *(const int4*)(Wp + k0);
        __syncthreads();
        As[lq*4+0][lr] = av.x; As[lq*4+1][lr] = av.y;
        As[lq*4+2][lr] = av.z; As[lq*4+3][lr] = av.w;
        Ws[lq*4+0][lr] = (float)wv.x; Ws[lq*4+1][lr] = (float)wv.y;
        Ws[lq*4+2][lr] = (float)wv.z; Ws[lq*4+3][lr] = (float)wv.w;
        __syncthreads();
#pragma unroll
        for (int kk = 0; kk < 16; kk++) {
            const float4 a4 = *(const float4*)&As[kk][ty * 4];
            const float4 b4 = *(const float4*)&Ws[kk][tx * 4];
            FMA16(a4, b4, acc);
        }
    }
    const int m0 = bm + ty * 4, n0 = bn + tx * 4;
    const float4 scv = *(const float4*)(sc + n0);
    const float4 bsv = *(const float4*)(bias + n0);
#pragma unroll
    for (int i = 0; i < 4; i++) {
        const int m = m0 + i;
        float4 o;
        o.x = acc[i][0] * scv.x + bsv.x;
        o.y = acc[i][1] * scv.y + bsv.y;
        o.z = acc[i][2] * scv.z + bsv.z;
        o.w = acc[i][3] * scv.w + bsv.w;
        const float* xam = xa + m * 16;
#pragma unroll
        for (int r = 0; r < 16; r++) {
            const float xr = xam[r];
            const float4 lbv = *(const float4*)(lb + (long)r * N + n0);
            o.x += xr * lbv.x; o.y += xr * lbv.y; o.z += xr * lbv.z; o.w += xr * lbv.w;
        }
        if (res) {
            const float4 rv = *(const float4*)(res + (long)m * N + n0);
            o.x += rv.x; o.y += rv.y; o.z += rv.z; o.w += rv.w;
        }
        *(float4*)(Cout + (long)m * N + n0) = o;
    }
}

// ---------------- attention ----------------
__global__ __launch_bounds__(256) void score_kernel(const float* __restrict__ q,
                                                    const float* __restrict__ kbuf,
                                                    float* __restrict__ probs) {
    const int bx = blockIdx.x, by = blockIdx.y, h = blockIdx.z;
    if (bx > by) return;   // strictly upper tiles never read (softmax skips, then zero-fills)
    __shared__ __align__(16) float Qs[16][68];
    __shared__ __align__(16) float Ks[16][68];
    const int tid = threadIdx.x;
    const int tx = tid & 15, ty = tid >> 4;
    const int lr = tid >> 2, lq = tid & 3;
    const float* Qp = q + (by * 64 + lr) * 2048 + h * 64 + lq * 4;
    const float* Kp = kbuf + (bx * 64 + lr) * 512 + (h >> 2) * 64 + lq * 4;
    float acc[4][4] = {};
    for (int k0 = 0; k0 < 64; k0 += 16) {
        const float4 av = *(const float4*)(Qp + k0);
        const float4 bv = *(const float4*)(Kp + k0);
        __syncthreads();
        Qs[lq*4+0][lr] = av.x; Qs[lq*4+1][lr] = av.y;
        Qs[lq*4+2][lr] = av.z; Qs[lq*4+3][lr] = av.w;
        Ks[lq*4+0][lr] = bv.x; Ks[lq*4+1][lr] = bv.y;
        Ks[lq*4+2][lr] = bv.z; Ks[lq*4+3][lr] = bv.w;
        __syncthreads();
#pragma unroll
        for (int kk = 0; kk < 16; kk++) {
            const float4 a4 = *(const float4*)&Qs[kk][ty * 4];
            const float4 b4 = *(const float4*)&Ks[kk][tx * 4];
            FMA16(a4, b4, acc);
        }
    }
#pragma unroll
    for (int i = 0; i < 4; i++) {
        float4 o;
        o.x = acc[i][0] * 0.125f; o.y = acc[i][1] * 0.125f;
        o.z = acc[i][2] * 0.125f; o.w = acc[i][3] * 0.125f;
        *(float4*)(probs + (long)((h * 1024) + by * 64 + ty * 4 + i) * 1024 + bx * 64 + tx * 4) = o;
    }
}

__global__ __launch_bounds__(256) void softmax_kernel(float* __restrict__ probs) {
    const int row = blockIdx.x;       // h*1024 + qi
    const int qi = row & 1023;
    float* p = probs + (long)row * 1024;
    const int tid = threadIdx.x;
    __shared__ float red[256];
    float m = -3.4e38f;
    for (int i = tid; i <= qi; i += 256) m = fmaxf(m, p[i]);
    red[tid] = m; __syncthreads();
    for (int off = 128; off; off >>= 1) { if (tid < off) red[tid] = fmaxf(red[tid], red[tid + off]); __syncthreads(); }
    m = red[0]; __syncthreads();
    float s = 0.f;
    for (int i = tid; i <= qi; i += 256) { float e = expf(p[i] - m); p[i] = e; s += e; }
    red[tid] = s; __syncthreads();
    for (int off = 128; off; off >>= 1) { if (tid < off) red[tid] += red[tid + off]; __syncthreads(); }
    const float inv = 1.f / red[0];
    for (int i = tid; i < 1024; i += 256) p[i] = (i <= qi) ? p[i] * inv : 0.f;
}

__global__ __launch_bounds__(256) void av_kernel(const float* __restrict__ probs,
                                                 const float* __restrict__ vbuf,
                                                 float* __restrict__ obuf) {
    const int by = blockIdx.x, h = blockIdx.y;
    __shared__ __align__(16) float Ps[16][68];
    __shared__ __align__(16) float Vs[16][64];
    const int tid = threadIdx.x;
    const int tx = tid & 15, ty = tid >> 4;
    const int lr = tid >> 2, lq = tid & 3;
    const int vk = tid >> 4, vd = tid & 15;
    const float* Pp = probs + (long)((h * 1024) + by * 64 + lr) * 1024 + lq * 4;
    const int kmax = (by + 1) * 64;   // probs exactly 0 past diagonal
    float acc[4][4] = {};
    for (int k0 = 0; k0 < kmax; k0 += 16) {
        const float4 pv = *(const float4*)(Pp + k0);
        const float4 vv = *(const float4*)(vbuf + (k0 + vk) * 512 + (h >> 2) * 64 + vd * 4);
        __syncthreads();
        Ps[lq*4+0][lr] = pv.x; Ps[lq*4+1][lr] = pv.y;
        Ps[lq*4+2][lr] = pv.z; Ps[lq*4+3][lr] = pv.w;
        *(float4*)&Vs[vk][vd * 4] = vv;
        __syncthreads();
#pragma unroll
        for (int kk = 0; kk < 16; kk++) {
            const float4 a4 = *(const float4*)&Ps[kk][ty * 4];
            const float4 b4 = *(const float4*)&Vs[kk][tx * 4];
            FMA16(a4, b4, acc);
        }
    }
#pragma unroll
    for (int i = 0; i < 4; i++) {
        float4 o = make_float4(acc[i][0], acc[i][1], acc[i][2], acc[i][3]);
        *(float4*)(obuf + (by * 64 + ty * 4 + i) * 2048 + h * 64 + tx * 4) = o;
    }
}

// ---------------- exact quantile via radix select on float bits ----------------
__global__ void sel_init_kernel(unsigned* __restrict__ sel, unsigned* __restrict__ hist, unsigned k) {
    const int i = blockIdx.x * 256 + threadIdx.x;
    if (i < 4096) hist[i] = 0u;
    if (i == 0) { sel[0] = 0u; sel[1] = k; }
}

__global__ __launch_bounds__(256) void hist_pass_kernel(const float* __restrict__ vals, long n,
                                                        const unsigned* __restrict__ sel,
                                                        unsigned* __restrict__ hist,
                                                        int shift, unsigned prefmask) {
    __shared__ unsigned h[4096];
    for (int i = threadIdx.x; i < 4096; i += 256) h[i] = 0u;
    __syncthreads();
    const unsigned prefix = sel[0];
    const long stride = (long)gridDim.x * 256;
    unsigned zcnt = 0;
    for (long i = (long)blockIdx.x * 256 + threadIdx.x; i < n; i += stride) {
        const unsigned b = __float_as_uint(vals[i]);
        if ((b & prefmask) == prefix) {
            if (b == 0u) zcnt++;                       // ~50% exact zeros: avoid hot atomic
            else atomicAdd(&h[(b >> shift) & 4095], 1u);
        }
    }
    if (zcnt) atomicAdd(&h[0], zcnt);
    __syncthreads();
    for (int i = threadIdx.x; i < 4096; i += 256) if (h[i]) atomicAdd(&hist[i], h[i]);
}

__global__ void resolve_pass_kernel(unsigned* __restrict__ sel, unsigned* __restrict__ hist,
                                    int shift, int last, float* __restrict__ res, int slot) {
    if (blockIdx.x || threadIdx.x) return;
    const unsigned krem = sel[1];
    unsigned cum = 0; int found = 0;
    for (int b = 0; b < 4096; b++) {
        const unsigned c = hist[b]; hist[b] = 0u;
        if (!found) {
            if (cum + c > krem) { sel[0] |= ((unsigned)b) << shift; sel[1] = krem - cum; found = 1; }
            else cum += c;
        }
    }
    if (last) res[slot] = __uint_as_float(sel[0]);
}

__global__ void finalize_thr_kernel(const float* __restrict__ res, float* __restrict__ out) {
    if (threadIdx.x == 0) out[0] = res[0] + (res[1] - res[0]) * 0.45f;
}

// ---------------- host side ----------------
extern "C" void kernel_launch(void* const* d_in, const int* in_sizes, int n_in,
                              void* d_out, int out_size, void* d_ws, size_t ws_size,
                              hipStream_t stream) {
    (void)in_sizes; (void)n_in; (void)out_size; (void)ws_size;
    const float* x    = (const float*)d_in[0];
    const float* w1   = (const float*)d_in[1];
    const float* w2   = (const float*)d_in[2];
    const float* cosp = (const float*)d_in[3];
    const float* sinp = (const float*)d_in[4];
    // d_in[5] mask: implicit causal, unused
    const int*   wi_q   = (const int*)d_in[6];
    const float* sc_q   = (const float*)d_in[7];
    const float* b_q    = (const float*)d_in[8];
    const float* la_q   = (const float*)d_in[9];
    const float* lb_q   = (const float*)d_in[10];
    const int*   wi_k   = (const int*)d_in[11];
    const float* sc_k   = (const float*)d_in[12];
    const float* b_k    = (const float*)d_in[13];
    const float* la_k   = (const float*)d_in[14];
    const float* lb_k   = (const float*)d_in[15];
    const int*   wi_v   = (const int*)d_in[16];
    const float* sc_v   = (const float*)d_in[17];
    const float* b_v    = (const float*)d_in[18];
    const float* la_v   = (const float*)d_in[19];
    const float* lb_v   = (const float*)d_in[20];
    const int*   wi_o   = (const int*)d_in[21];
    const float* sc_o   = (const float*)d_in[22];
    const float* b_o    = (const float*)d_in[23];
    const float* la_o   = (const float*)d_in[24];
    const float* lb_o   = (const float*)d_in[25];
    const int*   wi_g   = (const int*)d_in[26];
    const float* sc_g   = (const float*)d_in[27];
    const float* b_g    = (const float*)d_in[28];
    const float* la_g   = (const float*)d_in[29];
    const float* lb_g   = (const float*)d_in[30];
    const int*   wi_u   = (const int*)d_in[31];
    const float* sc_u   = (const float*)d_in[32];
    const float* b_u    = (const float*)d_in[33];
    const float* la_u   = (const float*)d_in[34];
    const float* lb_u   = (const float*)d_in[35];
    const int*   wi_d   = (const int*)d_in[36];
    const float* sc_d   = (const float*)d_in[37];
    const float* b_d    = (const float*)d_in[38];
    const float* la_d   = (const float*)d_in[39];
    const float* lb_d   = (const float*)d_in[40];

    float* F    = (float*)d_ws;
    float* XN1  = F + WS_XN1;
    float* Q    = F + WS_Q;
    float* K    = F + WS_KB;
    float* V    = F + WS_VB;
    float* O    = F + WS_OB;
    float* XMED = F + WS_XMED;
    float* XN2  = F + WS_XN2;
    float* PROBS= F + WS_PROBS;
    float* GATE = F + WS_GATE;
    float* UP   = F + WS_UP;
    float* HAD  = F + WS_HAD;
    float* XA   = F + WS_XA;
    unsigned* CMX   = (unsigned*)(F + CM_X);
    unsigned* CMXN1 = (unsigned*)(F + CM_XN1);
    unsigned* CMQ   = (unsigned*)(F + CM_Qb);
    unsigned* CMK   = (unsigned*)(F + CM_Kb);
    unsigned* CMV   = (unsigned*)(F + CM_Vb);
    unsigned* CMO   = (unsigned*)(F + CM_Ob);
    unsigned* CMXM  = (unsigned*)(F + CM_XM);
    unsigned* CMXN2 = (unsigned*)(F + CM_XN2b);
    unsigned* CMG   = (unsigned*)(F + CM_GATE);
    unsigned* CMF   = (unsigned*)(F + CM_FN);
    unsigned* CMU   = (unsigned*)(F + CM_UPb);
    unsigned* CMH   = (unsigned*)(F + CM_HAD);
    int*      IDX0  = (int*)(F + WS_IDX);
    int*      IDX1  = IDX0 + 20;
    unsigned* HIST  = (unsigned*)(F + WS_HIST);
    unsigned* SEL   = (unsigned*)(F + WS_SEL);
    float*    RES   = F + WS_RES;
    float*    OUT   = (float*)d_out;

    // 0. zero all column-max accumulators
    zero_kernel<<<(CM_TOTAL + 255) / 256, 256, 0, stream>>>(CMX, CM_TOTAL);

    // 1. rmsnorm1 + x channel pack + xn1 scale
    rmsnorm_kernel<<<1024, 256, 0, stream>>>(x, w1, XN1);
    colabsmax_kernel<<<dim3(8, 64), 256, 0, stream>>>(x, 1024, 2048, CMX, 0);
    topk20_kernel<<<1, 256, 0, stream>>>(CMX, OUT + O_XIDX, IDX0);
    packscale_kernel<<<8, 256, 0, stream>>>(CMX, IDX0, OUT + O_XSC, 2048);
    colabsmax_kernel<<<dim3(8, 64), 256, 0, stream>>>(XN1, 1024, 2048, CMXN1, 0);
    scale_fin_kernel<<<8, 256, 0, stream>>>(CMXN1, OUT + O_XN1S, 2048);

    // 2. q/k/v projections
    lora_xa_kernel<<<1024, 256, 0, stream>>>(XN1, la_q, XA, 2048);
    gemm_qint_kernel<<<dim3(32, 16), 256, 0, stream>>>(XN1, wi_q, sc_q, b_q, XA, lb_q, nullptr, Q, 2048, 2048);
    lora_xa_kernel<<<1024, 256, 0, stream>>>(XN1, la_k, XA, 2048);
    gemm_qint_kernel<<<dim3(8, 16), 256, 0, stream>>>(XN1, wi_k, sc_k, b_k, XA, lb_k, nullptr, K, 512, 2048);
    lora_xa_kernel<<<1024, 256, 0, stream>>>(XN1, la_v, XA, 2048);
    gemm_qint_kernel<<<dim3(8, 16), 256, 0, stream>>>(XN1, wi_v, sc_v, b_v, XA, lb_v, nullptr, V, 512, 2048);

    // 3. rope + q/k/v scales
    rope_kernel<<<4096, 256, 0, stream>>>(Q, cosp, sinp, 32);
    rope_kernel<<<1024, 256, 0, stream>>>(K, cosp, sinp, 8);
    colabsmax_kernel<<<dim3(1, 256), 256, 0, stream>>>(Q, 32768, 64, CMQ, 0);
    scale_fin_kernel<<<1, 256, 0, stream>>>(CMQ, OUT + O_QS, 64);
    colabsmax_kernel<<<dim3(1, 128), 256, 0, stream>>>(K, 8192, 64, CMK, 0);
    scale_fin_kernel<<<1, 256, 0, stream>>>(CMK, OUT + O_KS, 64);
    colabsmax_kernel<<<dim3(1, 128), 256, 0, stream>>>(V, 8192, 64, CMV, 0);
    scale_fin_kernel<<<1, 256, 0, stream>>>(CMV, OUT + O_VS, 64);

    // 4. attention
    score_kernel<<<dim3(16, 16, 32), 256, 0, stream>>>(Q, K, PROBS);
    softmax_kernel<<<32768, 256, 0, stream>>>(PROBS);
    av_kernel<<<dim3(16, 32), 256, 0, stream>>>(PROBS, V, O);
    colabsmax_kernel<<<dim3(8, 64), 256, 0, stream>>>(O, 1024, 2048, CMO, 0);
    scale_fin_kernel<<<8, 256, 0, stream>>>(CMO, OUT + O_OS, 2048);

    // 5. a_thr = quantile(probs, 0.95): ranks 31876709 / 31876710 of 33554432, frac 0.45
    const long NP = 33554432L;
    for (int s = 0; s < 2; s++) {
        const unsigned kr = s ? 31876710u : 31876709u;
        sel_init_kernel<<<16, 256, 0, stream>>>(SEL, HIST, kr);
        hist_pass_kernel<<<4096, 256, 0, stream>>>(PROBS, NP, SEL, HIST, 20, 0x00000000u);
        resolve_pass_kernel<<<1, 1, 0, stream>>>(SEL, HIST, 20, 0, RES, s);
        hist_pass_kernel<<<4096, 256, 0, stream>>>(PROBS, NP, SEL, HIST, 8, 0xFFF00000u);
        resolve_pass_kernel<<<1, 1, 0, stream>>>(SEL, HIST, 8, 0, RES, s);
        hist_pass_kernel<<<4096, 256, 0, stream>>>(PROBS, NP, SEL, HIST, 0, 0xFFFFFF00u);
        resolve_pass_kernel<<<1, 1, 0, stream>>>(SEL, HIST, 0, 1, RES, s);
    }
    finalize_thr_kernel<<<1, 64, 0, stream>>>(RES, OUT + O_ATHR);

    // 6. o projection (+residual x) -> x_med; x_med pack; rmsnorm2
    lora_xa_kernel<<<1024, 256, 0, stream>>>(O, la_o, XA, 2048);
    gemm_qint_kernel<<<dim3(32, 16), 256, 0, stream>>>(O, wi_o, sc_o, b_o, XA, lb_o, x, XMED, 2048, 2048);
    colabsmax_kernel<<<dim3(8, 64), 256, 0, stream>>>(XMED, 1024, 2048, CMXM, 0);
    topk20_kernel<<<1, 256, 0, stream>>>(CMXM, OUT + O_XMIDX, IDX1);
    packscale_kernel<<<8, 256, 0, stream>>>(CMXM, IDX1, OUT + O_XMS, 2048);
    rmsnorm_kernel<<<1024, 256, 0, stream>>>(XMED, w2, XN2);
    colabsmax_kernel<<<dim3(8, 64), 256, 0, stream>>>(XN2, 1024, 2048, CMXN2, 0);
    scale_fin_kernel<<<8, 256, 0, stream>>>(CMXN2, OUT + O_XN2S, 2048);

    // 7. MLP (gate/up overwrite PROBS region -- quantile already consumed it)
    lora_xa_kernel<<<1024, 256, 0, stream>>>(XN2, la_g, XA, 2048);
    gemm_qint_kernel<<<dim3(88, 16), 256, 0, stream>>>(XN2, wi_g, sc_g, b_g, XA, lb_g, nullptr, GATE, 5632, 2048);
    lora_xa_kernel<<<1024, 256, 0, stream>>>(XN2, la_u, XA, 2048);
    gemm_qint_kernel<<<dim3(88, 16), 256, 0, stream>>>(XN2, wi_u, sc_u, b_u, XA, lb_u, nullptr, UP, 5632, 2048);
    colabsmax_kernel<<<dim3(22, 32), 256, 0, stream>>>(GATE, 1024, 5632, CMG, 0);
    scale_fin_kernel<<<22, 256, 0, stream>>>(CMG, OUT + O_GATES, 5632);
    colabsmax_kernel<<<dim3(22, 32), 256, 0, stream>>>(GATE, 1024, 5632, CMF, 1);
    scale_fin_kernel<<<22, 256, 0, stream>>>(CMF, OUT + O_FNS, 5632);
    colabsmax_kernel<<<dim3(22, 32), 256, 0, stream>>>(UP, 1024, 5632, CMU, 0);
    scale_fin_kernel<<<22, 256, 0, stream>>>(CMU, OUT + O_UPS, 5632);
    hadamard_kernel<<<22528, 256, 0, stream>>>(GATE, UP, HAD, 5767168);
    colabsmax_kernel<<<dim3(22, 32), 256, 0, stream>>>(HAD, 1024, 5632, CMH, 0);
    scale_fin_kernel<<<22, 256, 0, stream>>>(CMH, OUT + O_HADS, 5632);

    // 8. down projection (+residual x_med) -> x_out (directly into d_out)
    lora_xa_kernel<<<1024, 256, 0, stream>>>(HAD, la_d, XA, 5632);
    gemm_qint_kernel<<<dim3(32, 16), 256, 0, stream>>>(HAD, wi_d, sc_d, b_d, XA, lb_d, XMED, OUT + O_XOUT, 2048, 5632);
}

// Round 2
// 2309.532 us; speedup vs baseline: 2.7107x; 2.7107x over previous
//
#include <hip/hip_runtime.h>

// ---------------- problem dims ----------------
// B=1, S=1024, C=2048, H=32, D=64, HKV=8, R=16, FF=5632, Q_BIT=4 (qmax=7)

// ---------------- ws layout (float offsets) ----------------
#define WS_XN1   0L
#define WS_Q     2097152L
#define WS_KB    4194304L
#define WS_VB    4718592L
#define WS_OB    5242880L
#define WS_XMED  7340032L
#define WS_XN2   9437184L
#define WS_PROBS 11534336L
#define WS_GATE  (WS_PROBS)
#define WS_UP    (WS_PROBS + 5767168L)
#define WS_HAD   (WS_PROBS + 11534336L)
// bf16 scratch packed into the tail of the probs region (free when used):
#define BF_BASE  (WS_PROBS + 17301504L)
#define BF_XN1H  (BF_BASE + 0L)
#define BF_XN1L  (BF_BASE + 1048576L)
#define BF_OH    (BF_BASE + 2097152L)
#define BF_OL    (BF_BASE + 3145728L)
#define BF_XN2H  (BF_BASE + 4194304L)
#define BF_XN2L  (BF_BASE + 5242880L)
#define BF_HADH  (BF_BASE + 6291456L)
#define BF_HADL  (BF_BASE + 9175040L)
#define BF_XAH   (BF_BASE + 12058624L)
#define BF_XAL   (BF_BASE + 12075008L)
#define BF_LBT   (BF_BASE + 12091392L)
#define WS_SMALL 45088768L
#define CM_X     (WS_SMALL + 0L)
#define CM_XN1   (WS_SMALL + 2048L)
#define CM_Qb    (WS_SMALL + 4096L)
#define CM_Kb    (WS_SMALL + 4160L)
#define CM_Vb    (WS_SMALL + 4224L)
#define CM_Ob    (WS_SMALL + 4288L)
#define CM_XM    (WS_SMALL + 6336L)
#define CM_XN2b  (WS_SMALL + 8384L)
#define CM_GATE  (WS_SMALL + 10432L)
#define CM_FN    (WS_SMALL + 16064L)
#define CM_UPb   (WS_SMALL + 21696L)
#define CM_HAD   (WS_SMALL + 27328L)
#define CM_TOTAL 32960
#define WS_IDX   (WS_SMALL + 32960L)
#define WS_HIST  (WS_IDX + 64L)
#define WS_SEL   (WS_HIST + 4096L)
#define WS_RES   (WS_SEL + 8L)

// ---------------- out layout (float offsets) ----------------
#define O_XOUT  0L
#define O_XIDX  2097152L
#define O_XSC   2097172L
#define O_XN1S  2099220L
#define O_QS    2101268L
#define O_KS    2101332L
#define O_VS    2101396L
#define O_ATHR  2101460L
#define O_OS    2101461L
#define O_XMIDX 2103509L
#define O_XMS   2103529L
#define O_XN2S  2105577L
#define O_GATES 2107625L
#define O_UPS   2113257L
#define O_FNS   2118889L
#define O_HADS  2124521L

typedef float  floatx4 __attribute__((ext_vector_type(4)));
typedef short  shortx8 __attribute__((ext_vector_type(8)));

static __device__ __forceinline__ unsigned short f2bf(float f) {
    unsigned u = __float_as_uint(f);
    return (unsigned short)((u + 0x7FFFu + ((u >> 16) & 1u)) >> 16);
}
static __device__ __forceinline__ float bf2f(unsigned short b) {
    return __uint_as_float(((unsigned)b) << 16);
}
static __device__ __forceinline__ unsigned pack_bf2(int a, int b) {
    // ints in [-128,127] are exact in bf16; low 16 mantissa bits are zero
    return (__float_as_uint((float)a) >> 16) | (__float_as_uint((float)b) & 0xFFFF0000u);
}

#define FMA16(a4,b4,acc) do { \
  acc[0][0] += a4.x*b4.x; acc[0][1] += a4.x*b4.y; acc[0][2] += a4.x*b4.z; acc[0][3] += a4.x*b4.w; \
  acc[1][0] += a4.y*b4.x; acc[1][1] += a4.y*b4.y; acc[1][2] += a4.y*b4.z; acc[1][3] += a4.y*b4.w; \
  acc[2][0] += a4.z*b4.x; acc[2][1] += a4.z*b4.y; acc[2][2] += a4.z*b4.z; acc[2][3] += a4.z*b4.w; \
  acc[3][0] += a4.w*b4.x; acc[3][1] += a4.w*b4.y; acc[3][2] += a4.w*b4.z; acc[3][3] += a4.w*b4.w; \
} while (0)

// ---------------- small utility kernels ----------------
__global__ void zero_kernel(unsigned* __restrict__ p, int n) {
    int i = blockIdx.x * 256 + threadIdx.x;
    if (i < n) p[i] = 0u;
}

__global__ __launch_bounds__(256) void rmsnorm_kernel(const float* __restrict__ x,
                                                      const float* __restrict__ w,
                                                      float* __restrict__ out) {
    const int row = blockIdx.x;
    const int tid = threadIdx.x;
    const float* xr = x + row * 2048;
    float s = 0.f;
    for (int i = tid; i < 2048; i += 256) { float v = xr[i]; s += v * v; }
    __shared__ float red[256];
    red[tid] = s; __syncthreads();
    for (int off = 128; off; off >>= 1) { if (tid < off) red[tid] += red[tid + off]; __syncthreads(); }
    const float rstd = 1.0f / sqrtf(red[0] / 2048.0f + 1e-5f);
    float* orow = out + row * 2048;
    for (int i = tid; i < 2048; i += 256) orow[i] = xr[i] * rstd * w[i];
}

__global__ void colabsmax_kernel(const float* __restrict__ in, int M, int N,
                                 unsigned* __restrict__ outb, int mode) {
    const int c = blockIdx.x * 256 + threadIdx.x;
    if (c >= N) return;
    float loc = 0.f;
    for (int r = blockIdx.y; r < M; r += gridDim.y) {
        float v = in[(long)r * N + c];
        if (mode) v = v / (1.f + expf(-v));
        loc = fmaxf(loc, fabsf(v));
    }
    atomicMax(outb + c, __float_as_uint(loc));
}

__global__ void scale_fin_kernel(const unsigned* __restrict__ bits, float* __restrict__ out, int n) {
    int i = blockIdx.x * 256 + threadIdx.x;
    if (i < n) out[i] = __uint_as_float(bits[i]) / 7.0f + 1e-8f;
}

__global__ __launch_bounds__(256) void topk20_kernel(const unsigned* __restrict__ cmaxbits,
                                                     float* __restrict__ out_idx_f,
                                                     int* __restrict__ out_idx_i) {
    __shared__ float vals[2048];
    __shared__ float rv[256];
    __shared__ int   ri[256];
    const int tid = threadIdx.x;
    for (int i = tid; i < 2048; i += 256) vals[i] = __uint_as_float(cmaxbits[i]);
    __syncthreads();
    for (int t = 0; t < 20; t++) {
        float bv = -1.f; int bi = 1 << 30;
        for (int i = tid; i < 2048; i += 256) {
            float v = vals[i];
            if (v > bv) { bv = v; bi = i; }
        }
        rv[tid] = bv; ri[tid] = bi; __syncthreads();
        for (int off = 128; off; off >>= 1) {
            if (tid < off) {
                float v2 = rv[tid + off]; int i2 = ri[tid + off];
                if (v2 > rv[tid] || (v2 == rv[tid] && i2 < ri[tid])) { rv[tid] = v2; ri[tid] = i2; }
            }
            __syncthreads();
        }
        if (tid == 0) { out_idx_f[t] = (float)ri[0]; out_idx_i[t] = ri[0]; vals[ri[0]] = -1.f; }
        __syncthreads();
    }
}

__global__ void packscale_kernel(const unsigned* __restrict__ cmaxbits,
                                 const int* __restrict__ idx, float* __restrict__ out, int n) {
    const int c = blockIdx.x * 256 + threadIdx.x;
    if (c >= n) return;
    bool outl = false;
    for (int t = 0; t < 20; t++) outl |= (idx[t] == c);
    const float m = __uint_as_float(cmaxbits[c]);
    out[c] = outl ? 1e-8f : (m / 7.0f + 1e-8f);
}

// xa = A @ la  -> hi/lo bf16, zero-padded [M][32]
__global__ __launch_bounds__(256) void lora_xa_kernel(const float* __restrict__ A,
                                                      const float* __restrict__ la,
                                                      unsigned short* __restrict__ xah,
                                                      unsigned short* __restrict__ xal, int K) {
    const int m = blockIdx.x;
    const int tid = threadIdx.x;
    const int r = tid & 15, g = tid >> 4;
    float s = 0.f;
    const float* Am = A + (long)m * K;
    for (int k = g; k < K; k += 16) s += Am[k] * la[k * 16 + r];
    __shared__ float red[256];
    red[tid] = s; __syncthreads();
    for (int off = 128; off >= 16; off >>= 1) { if (tid < off) red[tid] += red[tid + off]; __syncthreads(); }
    if (tid < 16) {
        const float v = red[tid];
        const unsigned short h = f2bf(v);
        xah[m * 32 + tid] = h;
        xal[m * 32 + tid] = f2bf(v - bf2f(h));
    } else if (tid < 32) {
        xah[m * 32 + tid] = 0; xal[m * 32 + tid] = 0;
    }
}

// fp32 -> bf16 hi/lo split
__global__ void hilo_kernel(const float* __restrict__ in, unsigned short* __restrict__ hi,
                            unsigned short* __restrict__ lo, long n4) {
    const long i = (long)blockIdx.x * 256 + threadIdx.x;
    if (i >= n4) return;
    const float4 v = *(const float4*)(in + i * 4);
    ushort4 h, l;
    h.x = f2bf(v.x); l.x = f2bf(v.x - bf2f(h.x));
    h.y = f2bf(v.y); l.y = f2bf(v.y - bf2f(h.y));
    h.z = f2bf(v.z); l.z = f2bf(v.z - bf2f(h.z));
    h.w = f2bf(v.w); l.w = f2bf(v.w - bf2f(h.w));
    *(ushort4*)(hi + i * 4) = h;
    *(ushort4*)(lo + i * 4) = l;
}

// lbT[n][r] = lb[r][n] / sc[n] in bf16, padded to [N][32]
__global__ void lbt_kernel(const float* __restrict__ lb, const float* __restrict__ sc,
                           unsigned short* __restrict__ out, int N) {
    const int n = blockIdx.x * 256 + threadIdx.x;
    if (n >= N) return;
    const float inv = 1.0f / sc[n];
    for (int r = 0; r < 16; r++) out[n * 32 + r] = f2bf(lb[r * N + n] * inv);
    for (int r = 16; r < 32; r++) out[n * 32 + r] = 0;
}

__global__ void rope_kernel(float* __restrict__ x, const float* __restrict__ cs,
                            const float* __restrict__ sn, int nh) {
    const int idx = blockIdx.x * 256 + threadIdx.x;
    const int tot = 1024 * nh * 32;
    if (idx >= tot) return;
    const int d = idx & 31;
    const int h = (idx >> 5) % nh;
    const int s = (idx >> 5) / nh;
    float* p = x + s * (nh * 64) + h * 64;
    const float x1 = p[d], x2 = p[d + 32];
    const float c1 = cs[s * 64 + d],      s1 = sn[s * 64 + d];
    const float c2 = cs[s * 64 + d + 32], s2 = sn[s * 64 + d + 32];
    p[d]      = x1 * c1 - x2 * s1;
    p[d + 32] = x2 * c2 + x1 * s2;
}

__global__ void hadamard_kernel(const float* __restrict__ gate, const float* __restrict__ up,
                                float* __restrict__ had, int n) {
    const int i = blockIdx.x * 256 + threadIdx.x;
    if (i < n) {
        const float g = gate[i];
        const float fn = g / (1.f + expf(-g));
        had[i] = up[i] * fn;
    }
}

// ---------------- MFMA GEMM ----------------
// C[m][n] = (sum_k bf16(A)[m][k]*Wbf[n][k] + xa[m]·lbT[n]) * sc[n] + bias[n] (+res)
// A supplied as hi/lo bf16 [M][K]; W int [N][K] converted to bf16 on the fly;
// LoRA folded as one extra K-step from XaH/XaL [M][32] and LbT [N][32].
__global__ __launch_bounds__(256) void gemm_mfma_kernel(
    const unsigned short* __restrict__ Ah, const unsigned short* __restrict__ Al,
    const int* __restrict__ Wi,
    const unsigned short* __restrict__ XaH, const unsigned short* __restrict__ XaL,
    const unsigned short* __restrict__ LbT,
    const float* __restrict__ sc, const float* __restrict__ bias,
    const float* __restrict__ res, float* __restrict__ Cout,
    int N, int K)
{
    __shared__ short AsH[128][40];
    __shared__ short AsL[128][40];
    __shared__ short Bs[128][40];
    const int tid  = threadIdx.x;
    const int bm   = blockIdx.y * 128, bn = blockIdx.x * 128;
    const int wave = tid >> 6, lane = tid & 63;
    const int wm   = (wave >> 1) * 64, wn = (wave & 1) * 64;
    const int l15  = lane & 15, l4 = lane >> 4;
    const int ra   = tid >> 1;
    const int ca   = (tid & 1) * 16;

    floatx4 acc[4][4];
#pragma unroll
    for (int i = 0; i < 4; i++)
#pragma unroll
        for (int j = 0; j < 4; j++) acc[i][j] = (floatx4){0.f, 0.f, 0.f, 0.f};

    const int iters = K >> 5;
    for (int iter = 0; iter <= iters; iter++) {
        uint4 h0, h1, l0, l1, b0, b1;
        if (iter < iters) {
            const size_t offA = (size_t)(bm + ra) * K + iter * 32 + ca;
            h0 = *(const uint4*)(Ah + offA); h1 = *(const uint4*)(Ah + offA + 8);
            l0 = *(const uint4*)(Al + offA); l1 = *(const uint4*)(Al + offA + 8);
            const size_t offB = (size_t)(bn + ra) * K + iter * 32 + ca;
            const int4 w0 = *(const int4*)(Wi + offB);
            const int4 w1 = *(const int4*)(Wi + offB + 4);
            const int4 w2 = *(const int4*)(Wi + offB + 8);
            const int4 w3 = *(const int4*)(Wi + offB + 12);
            b0.x = pack_bf2(w0.x, w0.y); b0.y = pack_bf2(w0.z, w0.w);
            b0.z = pack_bf2(w1.x, w1.y); b0.w = pack_bf2(w1.z, w1.w);
            b1.x = pack_bf2(w2.x, w2.y); b1.y = pack_bf2(w2.z, w2.w);
            b1.z = pack_bf2(w3.x, w3.y); b1.w = pack_bf2(w3.z, w3.w);
        } else {
            const size_t offA = (size_t)(bm + ra) * 32 + ca;
            h0 = *(const uint4*)(XaH + offA); h1 = *(const uint4*)(XaH + offA + 8);
            l0 = *(const uint4*)(XaL + offA); l1 = *(const uint4*)(XaL + offA + 8);
            const size_t offB = (size_t)(bn + ra) * 32 + ca;
            b0 = *(const uint4*)(LbT + offB); b1 = *(const uint4*)(LbT + offB + 8);
        }
        __syncthreads();
        *(uint4*)&AsH[ra][ca] = h0; *(uint4*)&AsH[ra][ca + 8] = h1;
        *(uint4*)&AsL[ra][ca] = l0; *(uint4*)&AsL[ra][ca + 8] = l1;
        *(uint4*)&Bs[ra][ca]  = b0; *(uint4*)&Bs[ra][ca + 8]  = b1;
        __syncthreads();

        shortx8 afh[4], afl[4], bf[4];
#pragma unroll
        for (int i = 0; i < 4; i++) {
            afh[i] = *(const shortx8*)&AsH[wm + i * 16 + l15][l4 * 8];
            afl[i] = *(const shortx8*)&AsL[wm + i * 16 + l15][l4 * 8];
            bf[i]  = *(const shortx8*)&Bs[wn + i * 16 + l15][l4 * 8];
        }
#pragma unroll
        for (int i = 0; i < 4; i++)
#pragma unroll
            for (int j = 0; j < 4; j++) {
                acc[i][j] = __builtin_amdgcn_mfma_f32_16x16x32_bf16(afh[i], bf[j], acc[i][j], 0, 0, 0);
                acc[i][j] = __builtin_amdgcn_mfma_f32_16x16x32_bf16(afl[i], bf[j], acc[i][j], 0, 0, 0);
            }
    }

    // epilogue: D row = l4*4 + reg, col = l15 within each 16x16 tile
#pragma unroll
    for (int j = 0; j < 4; j++) {
        const int n = bn + wn + j * 16 + l15;
        const float scn = sc[n], bsn = bias[n];
#pragma unroll
        for (int i = 0; i < 4; i++) {
            const int m0 = bm + wm + i * 16 + l4 * 4;
#pragma unroll
            for (int r = 0; r < 4; r++) {
                const int m = m0 + r;
                float v = acc[i][j][r] * scn + bsn;
                if (res) v += res[(size_t)m * N + n];
                Cout[(size_t)m * N + n] = v;
            }
        }
    }
}

// ---------------- attention (fp32, tiled) ----------------
__global__ __launch_bounds__(256) void score_kernel(const float* __restrict__ q,
                                                    const float* __restrict__ kbuf,
                                                    float* __restrict__ probs) {
    const int bx = blockIdx.x, by = blockIdx.y, h = blockIdx.z;
    if (bx > by) return;
    __shared__ __align__(16) float Qs[16][68];
    __shared__ __align__(16) float Ks[16][68];
    const int tid = threadIdx.x;
    const int tx = tid & 15, ty = tid >> 4;
    const int lr = tid >> 2, lq = tid & 3;
    const float* Qp = q + (by * 64 + lr) * 2048 + h * 64 + lq * 4;
    const float* Kp = kbuf + (bx * 64 + lr) * 512 + (h >> 2) * 64 + lq * 4;
    float acc[4][4] = {};
    for (int k0 = 0; k0 < 64; k0 += 16) {
        const float4 av = *(const float4*)(Qp + k0);
        const float4 bv = *(const float4*)(Kp + k0);
        __syncthreads();
        Qs[lq*4+0][lr] = av.x; Qs[lq*4+1][lr] = av.y;
        Qs[lq*4+2][lr] = av.z; Qs[lq*4+3][lr] = av.w;
        Ks[lq*4+0][lr] = bv.x; Ks[lq*4+1][lr] = bv.y;
        Ks[lq*4+2][lr] = bv.z; Ks[lq*4+3][lr] = bv.w;
        __syncthreads();
#pragma unroll
        for (int kk = 0; kk < 16; kk++) {
            const float4 a4 = *(const float4*)&Qs[kk][ty * 4];
            const float4 b4 = *(const float4*)&Ks[kk][tx * 4];
            FMA16(a4, b4, acc);
        }
    }
#pragma unroll
    for (int i = 0; i < 4; i++) {
        float4 o;
        o.x = acc[i][0] * 0.125f; o.y = acc[i][1] * 0.125f;
        o.z = acc[i][2] * 0.125f; o.w = acc[i][3] * 0.125f;
        *(float4*)(probs + (long)((h * 1024) + by * 64 + ty * 4 + i) * 1024 + bx * 64 + tx * 4) = o;
    }
}

__global__ __launch_bounds__(256) void softmax_kernel(float* __restrict__ probs) {
    const int row = blockIdx.x;
    const int qi = row & 1023;
    float* p = probs + (long)row * 1024;
    const int tid = threadIdx.x;
    __shared__ float red[256];
    float m = -3.4e38f;
    for (int i = tid; i <= qi; i += 256) m = fmaxf(m, p[i]);
    red[tid] = m; __syncthreads();
    for (int off = 128; off; off >>= 1) { if (tid < off) red[tid] = fmaxf(red[tid], red[tid + off]); __syncthreads(); }
    m = red[0]; __syncthreads();
    float s = 0.f;
    for (int i = tid; i <= qi; i += 256) { float e = expf(p[i] - m); p[i] = e; s += e; }
    red[tid] = s; __syncthreads();
    for (int off = 128; off; off >>= 1) { if (tid < off) red[tid] += red[tid + off]; __syncthreads(); }
    const float inv = 1.f / red[0];
    for (int i = tid; i < 1024; i += 256) p[i] = (i <= qi) ? p[i] * inv : 0.f;
}

__global__ __launch_bounds__(256) void av_kernel(const float* __restrict__ probs,
                                                 const float* __restrict__ vbuf,
                                                 float* __restrict__ obuf) {
    const int by = blockIdx.x, h = blockIdx.y;
    __shared__ __align__(16) float Ps[16][68];
    __shared__ __align__(16) float Vs[16][64];
    const int tid = threadIdx.x;
    const int tx = tid & 15, ty = tid >> 4;
    const int lr = tid >> 2, lq = tid & 3;
    const int vk = tid >> 4, vd = tid & 15;
    const float* Pp = probs + (long)((h * 1024) + by * 64 + lr) * 1024 + lq * 4;
    const int kmax = (by + 1) * 64;
    float acc[4][4] = {};
    for (int k0 = 0; k0 < kmax; k0 += 16) {
        const float4 pv = *(const float4*)(Pp + k0);
        const float4 vv = *(const float4*)(vbuf + (k0 + vk) * 512 + (h >> 2) * 64 + vd * 4);
        __syncthreads();
        Ps[lq*4+0][lr] = pv.x; Ps[lq*4+1][lr] = pv.y;
        Ps[lq*4+2][lr] = pv.z; Ps[lq*4+3][lr] = pv.w;
        *(float4*)&Vs[vk][vd * 4] = vv;
        __syncthreads();
#pragma unroll
        for (int kk = 0; kk < 16; kk++) {
            const float4 a4 = *(const float4*)&Ps[kk][ty * 4];
            const float4 b4 = *(const float4*)&Vs[kk][tx * 4];
            FMA16(a4, b4, acc);
        }
    }
#pragma unroll
    for (int i = 0; i < 4; i++) {
        float4 o = make_float4(acc[i][0], acc[i][1], acc[i][2], acc[i][3]);
        *(float4*)(obuf + (by * 64 + ty * 4 + i) * 2048 + h * 64 + tx * 4) = o;
    }
}

// ---------------- exact quantile via radix select on float bits ----------------
__global__ void sel_init_kernel(unsigned* __restrict__ sel, unsigned* __restrict__ hist, unsigned k) {
    const int i = blockIdx.x * 256 + threadIdx.x;
    if (i < 4096) hist[i] = 0u;
    if (i == 0) { sel[0] = 0u; sel[1] = k; }
}

__global__ __launch_bounds__(256) void hist_pass_kernel(const float* __restrict__ vals, long n,
                                                        const unsigned* __restrict__ sel,
                                                        unsigned* __restrict__ hist,
                                                        int shift, unsigned prefmask) {
    __shared__ unsigned h[4096];
    for (int i = threadIdx.x; i < 4096; i += 256) h[i] = 0u;
    __syncthreads();
    const unsigned prefix = sel[0];
    const long stride = (long)gridDim.x * 256;
    unsigned zcnt = 0;
    for (long i = (long)blockIdx.x * 256 + threadIdx.x; i < n; i += stride) {
        const unsigned b = __float_as_uint(vals[i]);
        if ((b & prefmask) == prefix) {
            if (b == 0u) zcnt++;
            else atomicAdd(&h[(b >> shift) & 4095], 1u);
        }
    }
    if (zcnt) atomicAdd(&h[0], zcnt);
    __syncthreads();
    for (int i = threadIdx.x; i < 4096; i += 256) if (h[i]) atomicAdd(&hist[i], h[i]);
}

// parallel resolve: 256-thread scan over 4096 bins (was single-thread: ~0.65 ms each!)
__global__ __launch_bounds__(256) void resolve_pass_kernel(unsigned* __restrict__ sel,
                                                           unsigned* __restrict__ hist,
                                                           int shift, int last,
                                                           float* __restrict__ res, int slot) {
    __shared__ unsigned part[256];
    __shared__ unsigned bpos, boff;
    const int tid = threadIdx.x;
    if (tid == 0) { bpos = 4095u; boff = 0u; }
    unsigned vals[16]; unsigned s = 0;
#pragma unroll
    for (int i = 0; i < 16; i++) { vals[i] = hist[tid * 16 + i]; s += vals[i]; }
    part[tid] = s; __syncthreads();
    for (int off = 1; off < 256; off <<= 1) {
        unsigned v = (tid >= off) ? part[tid - off] : 0u;
        __syncthreads();
        part[tid] += v;
        __syncthreads();
    }
    const unsigned krem = sel[1];
    unsigned c = part[tid] - s;   // exclusive prefix
#pragma unroll
    for (int i = 0; i < 16; i++) {
        if (krem >= c && krem < c + vals[i]) { bpos = tid * 16 + i; boff = krem - c; }
        c += vals[i];
    }
    __syncthreads();
    if (tid == 0) {
        const unsigned p = sel[0] | (bpos << shift);
        sel[0] = p; sel[1] = boff;
        if (last) res[slot] = __uint_as_float(p);
    }
    for (int i = 0; i < 16; i++) hist[tid * 16 + i] = 0u;
}

__global__ void finalize_thr_kernel(const float* __restrict__ res, float* __restrict__ out) {
    if (threadIdx.x == 0) out[0] = res[0] + (res[1] - res[0]) * 0.45f;
}

// ---------------- host side ----------------
extern "C" void kernel_launch(void* const* d_in, const int* in_sizes, int n_in,
                              void* d_out, int out_size, void* d_ws, size_t ws_size,
                              hipStream_t stream) {
    (void)in_sizes; (void)n_in; (void)out_size; (void)ws_size;
    const float* x    = (const float*)d_in[0];
    const float* w1   = (const float*)d_in[1];
    const float* w2   = (const float*)d_in[2];
    const float* cosp = (const float*)d_in[3];
    const float* sinp = (const float*)d_in[4];
    const int*   wi_q   = (const int*)d_in[6];
    const float* sc_q   = (const float*)d_in[7];
    const float* b_q    = (const float*)d_in[8];
    const float* la_q   = (const float*)d_in[9];
    const float* lb_q   = (const float*)d_in[10];
    const int*   wi_k   = (const int*)d_in[11];
    const float* sc_k   = (const float*)d_in[12];
    const float* b_k    = (const float*)d_in[13];
    const float* la_k   = (const float*)d_in[14];
    const float* lb_k   = (const float*)d_in[15];
    const int*   wi_v   = (const int*)d_in[16];
    const float* sc_v   = (const float*)d_in[17];
    const float* b_v    = (const float*)d_in[18];
    const float* la_v   = (const float*)d_in[19];
    const float* lb_v   = (const float*)d_in[20];
    const int*   wi_o   = (const int*)d_in[21];
    const float* sc_o   = (const float*)d_in[22];
    const float* b_o    = (const float*)d_in[23];
    const float* la_o   = (const float*)d_in[24];
    const float* lb_o   = (const float*)d_in[25];
    const int*   wi_g   = (const int*)d_in[26];
    const float* sc_g   = (const float*)d_in[27];
    const float* b_g    = (const float*)d_in[28];
    const float* la_g   = (const float*)d_in[29];
    const float* lb_g   = (const float*)d_in[30];
    const int*   wi_u   = (const int*)d_in[31];
    const float* sc_u   = (const float*)d_in[32];
    const float* b_u    = (const float*)d_in[33];
    const float* la_u   = (const float*)d_in[34];
    const float* lb_u   = (const float*)d_in[35];
    const int*   wi_d   = (const int*)d_in[36];
    const float* sc_d   = (const float*)d_in[37];
    const float* b_d    = (const float*)d_in[38];
    const float* la_d   = (const float*)d_in[39];
    const float* lb_d   = (const float*)d_in[40];

    float* F    = (float*)d_ws;
    float* XN1  = F + WS_XN1;
    float* Q    = F + WS_Q;
    float* K    = F + WS_KB;
    float* V    = F + WS_VB;
    float* O    = F + WS_OB;
    float* XMED = F + WS_XMED;
    float* XN2  = F + WS_XN2;
    float* PROBS= F + WS_PROBS;
    float* GATE = F + WS_GATE;
    float* UP   = F + WS_UP;
    float* HAD  = F + WS_HAD;
    unsigned short* XN1H = (unsigned short*)(F + BF_XN1H);
    unsigned short* XN1L = (unsigned short*)(F + BF_XN1L);
    unsigned short* OH   = (unsigned short*)(F + BF_OH);
    unsigned short* OL   = (unsigned short*)(F + BF_OL);
    unsigned short* XN2H = (unsigned short*)(F + BF_XN2H);
    unsigned short* XN2L = (unsigned short*)(F + BF_XN2L);
    unsigned short* HADH = (unsigned short*)(F + BF_HADH);
    unsigned short* HADL = (unsigned short*)(F + BF_HADL);
    unsigned short* XAH  = (unsigned short*)(F + BF_XAH);
    unsigned short* XAL  = (unsigned short*)(F + BF_XAL);
    unsigned short* LBT  = (unsigned short*)(F + BF_LBT);
    unsigned* CMX   = (unsigned*)(F + CM_X);
    unsigned* CMXN1 = (unsigned*)(F + CM_XN1);
    unsigned* CMQ   = (unsigned*)(F + CM_Qb);
    unsigned* CMK   = (unsigned*)(F + CM_Kb);
    unsigned* CMV   = (unsigned*)(F + CM_Vb);
    unsigned* CMO   = (unsigned*)(F + CM_Ob);
    unsigned* CMXM  = (unsigned*)(F + CM_XM);
    unsigned* CMXN2 = (unsigned*)(F + CM_XN2b);
    unsigned* CMG   = (unsigned*)(F + CM_GATE);
    unsigned* CMF   = (unsigned*)(F + CM_FN);
    unsigned* CMU   = (unsigned*)(F + CM_UPb);
    unsigned* CMH   = (unsigned*)(F + CM_HAD);
    int*      IDX0  = (int*)(F + WS_IDX);
    int*      IDX1  = IDX0 + 20;
    unsigned* HIST  = (unsigned*)(F + WS_HIST);
    unsigned* SEL   = (unsigned*)(F + WS_SEL);
    float*    RES   = F + WS_RES;
    float*    OUT   = (float*)d_out;

    // 0. zero column-max accumulators
    zero_kernel<<<(CM_TOTAL + 255) / 256, 256, 0, stream>>>(CMX, CM_TOTAL);

    // 1. rmsnorm1 + x channel pack + xn1 scale
    rmsnorm_kernel<<<1024, 256, 0, stream>>>(x, w1, XN1);
    colabsmax_kernel<<<dim3(8, 64), 256, 0, stream>>>(x, 1024, 2048, CMX, 0);
    topk20_kernel<<<1, 256, 0, stream>>>(CMX, OUT + O_XIDX, IDX0);
    packscale_kernel<<<8, 256, 0, stream>>>(CMX, IDX0, OUT + O_XSC, 2048);
    colabsmax_kernel<<<dim3(8, 64), 256, 0, stream>>>(XN1, 1024, 2048, CMXN1, 0);
    scale_fin_kernel<<<8, 256, 0, stream>>>(CMXN1, OUT + O_XN1S, 2048);

    // 2. q/k/v projections (MFMA, LoRA folded)
    hilo_kernel<<<2048, 256, 0, stream>>>(XN1, XN1H, XN1L, 524288);
    lora_xa_kernel<<<1024, 256, 0, stream>>>(XN1, la_q, XAH, XAL, 2048);
    lbt_kernel<<<8, 256, 0, stream>>>(lb_q, sc_q, LBT, 2048);
    gemm_mfma_kernel<<<dim3(16, 8), 256, 0, stream>>>(XN1H, XN1L, wi_q, XAH, XAL, LBT, sc_q, b_q, nullptr, Q, 2048, 2048);
    lora_xa_kernel<<<1024, 256, 0, stream>>>(XN1, la_k, XAH, XAL, 2048);
    lbt_kernel<<<2, 256, 0, stream>>>(lb_k, sc_k, LBT, 512);
    gemm_mfma_kernel<<<dim3(4, 8), 256, 0, stream>>>(XN1H, XN1L, wi_k, XAH, XAL, LBT, sc_k, b_k, nullptr, K, 512, 2048);
    lora_xa_kernel<<<1024, 256, 0, stream>>>(XN1, la_v, XAH, XAL, 2048);
    lbt_kernel<<<2, 256, 0, stream>>>(lb_v, sc_v, LBT, 512);
    gemm_mfma_kernel<<<dim3(4, 8), 256, 0, stream>>>(XN1H, XN1L, wi_v, XAH, XAL, LBT, sc_v, b_v, nullptr, V, 512, 2048);

    // 3. rope + q/k/v scales
    rope_kernel<<<4096, 256, 0, stream>>>(Q, cosp, sinp, 32);
    rope_kernel<<<1024, 256, 0, stream>>>(K, cosp, sinp, 8);
    colabsmax_kernel<<<dim3(1, 256), 256, 0, stream>>>(Q, 32768, 64, CMQ, 0);
    scale_fin_kernel<<<1, 256, 0, stream>>>(CMQ, OUT + O_QS, 64);
    colabsmax_kernel<<<dim3(1, 128), 256, 0, stream>>>(K, 8192, 64, CMK, 0);
    scale_fin_kernel<<<1, 256, 0, stream>>>(CMK, OUT + O_KS, 64);
    colabsmax_kernel<<<dim3(1, 128), 256, 0, stream>>>(V, 8192, 64, CMV, 0);
    scale_fin_kernel<<<1, 256, 0, stream>>>(CMV, OUT + O_VS, 64);

    // 4. attention
    score_kernel<<<dim3(16, 16, 32), 256, 0, stream>>>(Q, K, PROBS);
    softmax_kernel<<<32768, 256, 0, stream>>>(PROBS);
    av_kernel<<<dim3(16, 32), 256, 0, stream>>>(PROBS, V, O);
    colabsmax_kernel<<<dim3(8, 64), 256, 0, stream>>>(O, 1024, 2048, CMO, 0);
    scale_fin_kernel<<<8, 256, 0, stream>>>(CMO, OUT + O_OS, 2048);

    // 5. a_thr = quantile(probs, 0.95): ranks 31876709/31876710, frac 0.45
    const long NP = 33554432L;
    for (int s = 0; s < 2; s++) {
        const unsigned kr = s ? 31876710u : 31876709u;
        sel_init_kernel<<<16, 256, 0, stream>>>(SEL, HIST, kr);
        hist_pass_kernel<<<4096, 256, 0, stream>>>(PROBS, NP, SEL, HIST, 20, 0x00000000u);
        resolve_pass_kernel<<<1, 256, 0, stream>>>(SEL, HIST, 20, 0, RES, s);
        hist_pass_kernel<<<4096, 256, 0, stream>>>(PROBS, NP, SEL, HIST, 8, 0xFFF00000u);
        resolve_pass_kernel<<<1, 256, 0, stream>>>(SEL, HIST, 8, 0, RES, s);
        hist_pass_kernel<<<4096, 256, 0, stream>>>(PROBS, NP, SEL, HIST, 0, 0xFFFFFF00u);
        resolve_pass_kernel<<<1, 256, 0, stream>>>(SEL, HIST, 0, 1, RES, s);
    }
    finalize_thr_kernel<<<1, 64, 0, stream>>>(RES, OUT + O_ATHR);

    // 6. o projection (+residual x) -> x_med; pack; rmsnorm2
    hilo_kernel<<<2048, 256, 0, stream>>>(O, OH, OL, 524288);
    lora_xa_kernel<<<1024, 256, 0, stream>>>(O, la_o, XAH, XAL, 2048);
    lbt_kernel<<<8, 256, 0, stream>>>(lb_o, sc_o, LBT, 2048);
    gemm_mfma_kernel<<<dim3(16, 8), 256, 0, stream>>>(OH, OL, wi_o, XAH, XAL, LBT, sc_o, b_o, x, XMED, 2048, 2048);
    colabsmax_kernel<<<dim3(8, 64), 256, 0, stream>>>(XMED, 1024, 2048, CMXM, 0);
    topk20_kernel<<<1, 256, 0, stream>>>(CMXM, OUT + O_XMIDX, IDX1);
    packscale_kernel<<<8, 256, 0, stream>>>(CMXM, IDX1, OUT + O_XMS, 2048);
    rmsnorm_kernel<<<1024, 256, 0, stream>>>(XMED, w2, XN2);
    colabsmax_kernel<<<dim3(8, 64), 256, 0, stream>>>(XN2, 1024, 2048, CMXN2, 0);
    scale_fin_kernel<<<8, 256, 0, stream>>>(CMXN2, OUT + O_XN2S, 2048);

    // 7. MLP
    hilo_kernel<<<2048, 256, 0, stream>>>(XN2, XN2H, XN2L, 524288);
    lora_xa_kernel<<<1024, 256, 0, stream>>>(XN2, la_g, XAH, XAL, 2048);
    lbt_kernel<<<22, 256, 0, stream>>>(lb_g, sc_g, LBT, 5632);
    gemm_mfma_kernel<<<dim3(44, 8), 256, 0, stream>>>(XN2H, XN2L, wi_g, XAH, XAL, LBT, sc_g, b_g, nullptr, GATE, 5632, 2048);
    lora_xa_kernel<<<1024, 256, 0, stream>>>(XN2, la_u, XAH, XAL, 2048);
    lbt_kernel<<<22, 256, 0, stream>>>(lb_u, sc_u, LBT, 5632);
    gemm_mfma_kernel<<<dim3(44, 8), 256, 0, stream>>>(XN2H, XN2L, wi_u, XAH, XAL, LBT, sc_u, b_u, nullptr, UP, 5632, 2048);
    colabsmax_kernel<<<dim3(22, 32), 256, 0, stream>>>(GATE, 1024, 5632, CMG, 0);
    scale_fin_kernel<<<22, 256, 0, stream>>>(CMG, OUT + O_GATES, 5632);
    colabsmax_kernel<<<dim3(22, 32), 256, 0, stream>>>(GATE, 1024, 5632, CMF, 1);
    scale_fin_kernel<<<22, 256, 0, stream>>>(CMF, OUT + O_FNS, 5632);
    colabsmax_kernel<<<dim3(22, 32), 256, 0, stream>>>(UP, 1024, 5632, CMU, 0);
    scale_fin_kernel<<<22, 256, 0, stream>>>(CMU, OUT + O_UPS, 5632);
    hadamard_kernel<<<22528, 256, 0, stream>>>(GATE, UP, HAD, 5767168);
    colabsmax_kernel<<<dim3(22, 32), 256, 0, stream>>>(HAD, 1024, 5632, CMH, 0);
    scale_fin_kernel<<<22, 256, 0, stream>>>(CMH, OUT + O_HADS, 5632);

    // 8. down projection (+residual x_med) -> x_out
    hilo_kernel<<<5632, 256, 0, stream>>>(HAD, HADH, HADL, 1441792);
    lora_xa_kernel<<<1024, 256, 0, stream>>>(HAD, la_d, XAH, XAL, 5632);
    lbt_kernel<<<8, 256, 0, stream>>>(lb_d, sc_d, LBT, 2048);
    gemm_mfma_kernel<<<dim3(16, 8), 256, 0, stream>>>(HADH, HADL, wi_d, XAH, XAL, LBT, sc_d, b_d, XMED, OUT + O_XOUT, 2048, 5632);
}

// Round 3
// 1783.101 us; speedup vs baseline: 3.5111x; 1.2952x over previous
//
#include <hip/hip_runtime.h>

// ---------------- problem dims ----------------
// B=1, S=1024, C=2048, H=32, D=64, HKV=8, R=16, FF=5632, Q_BIT=4 (qmax=7)

// ---------------- ws layout (float offsets) ----------------
#define WS_XN1   0L
#define WS_Q     2097152L
#define WS_KB    4194304L
#define WS_VB    4718592L
#define WS_OB    5242880L
#define WS_XMED  7340032L
#define WS_XN2   9437184L
#define WS_PROBS 11534336L     // 33554432 floats, ends at 45088768
// ---- phase A aliases (inside probs; all dead before score writes probs) ----
#define PA        WS_PROBS
#define A_WQ      (PA + 0L)          // 2048x2048 bf16 = 2097152 floats
#define A_WK      (PA + 2097152L)    // 512x2048 bf16  = 524288
#define A_WV      (PA + 2621440L)
#define A_XN1H    (PA + 3145728L)    // 1024x2048 bf16 = 1048576
#define A_XN1L    (PA + 4194304L)
#define A_XAQH    (PA + 5242880L)    // 1024x32 bf16 = 16384
#define A_XAQL    (PA + 5259264L)
#define A_XAKH    (PA + 5275648L)
#define A_XAKL    (PA + 5292032L)
#define A_XAVH    (PA + 5308416L)
#define A_XAVL    (PA + 5324800L)
#define A_LBTQ    (PA + 5341184L)    // 2048x32 bf16 = 32768
#define A_LBTK    (PA + 5373952L)    // 512x32 = 8192
#define A_LBTV    (PA + 5382144L)
// ---- phase B aliases (inside probs; written only after quantile) ----
#define B_WO      (PA + 0L)          // 2097152
#define B_OH      (PA + 2097152L)    // 1048576
#define B_OL      (PA + 3145728L)
#define B_XAOH    (PA + 4194304L)
#define B_XAOL    (PA + 4210688L)
#define B_LBTO    (PA + 4227072L)    // 32768
#define B_WG      (PA + 4300800L)    // 5632x2048 bf16 = 5767168
#define B_WU      (PA + 10067968L)   // 5767168
#define B_XN2H    (PA + 15835136L)   // 1048576
#define B_XN2L    (PA + 16883712L)
#define B_XAGH    (PA + 17932288L)
#define B_XAGL    (PA + 17948672L)
#define B_XAUH    (PA + 17965056L)
#define B_XAUL    (PA + 17981440L)
#define B_LBTG    (PA + 17997824L)   // 90112
#define B_LBTU    (PA + 18087936L)
#define B_GATE    (PA + 18178048L)   // 5767168
#define B_UP      (PA + 23945216L)   // ends PA+29712384 < 33554432 OK
// after gate/up GEMM (WG/WU/XN2H dead):
#define B_HAD     (PA + 4300800L)    // WG slot, 5767168
#define B_WD      (PA + 10067968L)   // WU slot, 5767168
#define B_HADH    (PA + 0L)          // 2883584 (fits in WO+OH slots)
#define B_HADL    (PA + 18178048L)   // GATE slot (dead after hadamard), 2883584
#define B_XADH    (PA + 15835136L)   // XN2H slot
#define B_XADL    (PA + 15851520L)
#define B_LBTD    (PA + 15867904L)   // 32768
// ---- small stuff ----
#define WS_SMALL 45088768L
#define CM_X     (WS_SMALL + 0L)
#define CM_XN1   (WS_SMALL + 2048L)
#define CM_Qb    (WS_SMALL + 4096L)
#define CM_Kb    (WS_SMALL + 4160L)
#define CM_Vb    (WS_SMALL + 4224L)
#define CM_Ob    (WS_SMALL + 4288L)
#define CM_XM    (WS_SMALL + 6336L)
#define CM_XN2b  (WS_SMALL + 8384L)
#define CM_GATE  (WS_SMALL + 10432L)
#define CM_FN    (WS_SMALL + 16064L)
#define CM_UPb   (WS_SMALL + 21696L)
#define CM_HAD   (WS_SMALL + 27328L)
#define CM_TOTAL 32960
#define WS_IDX   (WS_SMALL + 32960L)
#define WS_HIST  (WS_IDX + 64L)
#define WS_SEL   (WS_HIST + 4096L)
#define WS_RES   (WS_SEL + 8L)

// ---------------- out layout (float offsets) ----------------
#define O_XOUT  0L
#define O_XIDX  2097152L
#define O_XSC   2097172L
#define O_XN1S  2099220L
#define O_QS    2101268L
#define O_KS    2101332L
#define O_VS    2101396L
#define O_ATHR  2101460L
#define O_OS    2101461L
#define O_XMIDX 2103509L
#define O_XMS   2103529L
#define O_XN2S  2105577L
#define O_GATES 2107625L
#define O_UPS   2113257L
#define O_FNS   2118889L
#define O_HADS  2124521L

typedef float  floatx4 __attribute__((ext_vector_type(4)));
typedef short  shortx8 __attribute__((ext_vector_type(8)));

static __device__ __forceinline__ unsigned short f2bf(float f) {
    unsigned u = __float_as_uint(f);
    return (unsigned short)((u + 0x7FFFu + ((u >> 16) & 1u)) >> 16);
}
static __device__ __forceinline__ float bf2f(unsigned short b) {
    return __uint_as_float(((unsigned)b) << 16);
}
static __device__ __forceinline__ void gload_lds16(const void* g, void* l) {
    __builtin_amdgcn_global_load_lds(
        (const __attribute__((address_space(1))) unsigned int*)g,
        (__attribute__((address_space(3))) unsigned int*)l, 16, 0, 0);
}

#define FMA16(a4,b4,acc) do { \
  acc[0][0] += a4.x*b4.x; acc[0][1] += a4.x*b4.y; acc[0][2] += a4.x*b4.z; acc[0][3] += a4.x*b4.w; \
  acc[1][0] += a4.y*b4.x; acc[1][1] += a4.y*b4.y; acc[1][2] += a4.y*b4.z; acc[1][3] += a4.y*b4.w; \
  acc[2][0] += a4.z*b4.x; acc[2][1] += a4.z*b4.y; acc[2][2] += a4.z*b4.z; acc[2][3] += a4.z*b4.w; \
  acc[3][0] += a4.w*b4.x; acc[3][1] += a4.w*b4.y; acc[3][2] += a4.w*b4.z; acc[3][3] += a4.w*b4.w; \
} while (0)

// ---------------- small utility kernels ----------------
__global__ void zero_kernel(unsigned* __restrict__ p, int n) {
    int i = blockIdx.x * 256 + threadIdx.x;
    if (i < n) p[i] = 0u;
}

__global__ __launch_bounds__(256) void rmsnorm_kernel(const float* __restrict__ x,
                                                      const float* __restrict__ w,
                                                      float* __restrict__ out) {
    const int row = blockIdx.x;
    const int tid = threadIdx.x;
    const float* xr = x + row * 2048;
    float s = 0.f;
    for (int i = tid; i < 2048; i += 256) { float v = xr[i]; s += v * v; }
    __shared__ float red[256];
    red[tid] = s; __syncthreads();
    for (int off = 128; off; off >>= 1) { if (tid < off) red[tid] += red[tid + off]; __syncthreads(); }
    const float rstd = 1.0f / sqrtf(red[0] / 2048.0f + 1e-5f);
    float* orow = out + row * 2048;
    for (int i = tid; i < 2048; i += 256) orow[i] = xr[i] * rstd * w[i];
}

__global__ void colabsmax_kernel(const float* __restrict__ in, int M, int N,
                                 unsigned* __restrict__ outb, int mode) {
    const int c = blockIdx.x * 256 + threadIdx.x;
    if (c >= N) return;
    float loc = 0.f;
    for (int r = blockIdx.y; r < M; r += gridDim.y) {
        float v = in[(long)r * N + c];
        if (mode) v = v / (1.f + expf(-v));
        loc = fmaxf(loc, fabsf(v));
    }
    atomicMax(outb + c, __float_as_uint(loc));
}

__global__ void scale_fin_kernel(const unsigned* __restrict__ bits, float* __restrict__ out, int n) {
    int i = blockIdx.x * 256 + threadIdx.x;
    if (i < n) out[i] = __uint_as_float(bits[i]) / 7.0f + 1e-8f;
}

__global__ __launch_bounds__(256) void topk20_kernel(const unsigned* __restrict__ cmaxbits,
                                                     float* __restrict__ out_idx_f,
                                                     int* __restrict__ out_idx_i) {
    __shared__ float vals[2048];
    __shared__ float rv[256];
    __shared__ int   ri[256];
    const int tid = threadIdx.x;
    for (int i = tid; i < 2048; i += 256) vals[i] = __uint_as_float(cmaxbits[i]);
    __syncthreads();
    for (int t = 0; t < 20; t++) {
        float bv = -1.f; int bi = 1 << 30;
        for (int i = tid; i < 2048; i += 256) {
            float v = vals[i];
            if (v > bv) { bv = v; bi = i; }
        }
        rv[tid] = bv; ri[tid] = bi; __syncthreads();
        for (int off = 128; off; off >>= 1) {
            if (tid < off) {
                float v2 = rv[tid + off]; int i2 = ri[tid + off];
                if (v2 > rv[tid] || (v2 == rv[tid] && i2 < ri[tid])) { rv[tid] = v2; ri[tid] = i2; }
            }
            __syncthreads();
        }
        if (tid == 0) { out_idx_f[t] = (float)ri[0]; out_idx_i[t] = ri[0]; vals[ri[0]] = -1.f; }
        __syncthreads();
    }
}

__global__ void packscale_kernel(const unsigned* __restrict__ cmaxbits,
                                 const int* __restrict__ idx, float* __restrict__ out, int n) {
    const int c = blockIdx.x * 256 + threadIdx.x;
    if (c >= n) return;
    bool outl = false;
    for (int t = 0; t < 20; t++) outl |= (idx[t] == c);
    const float m = __uint_as_float(cmaxbits[c]);
    out[c] = outl ? 1e-8f : (m / 7.0f + 1e-8f);
}

// xa = A @ la -> hi/lo bf16, zero-padded [M][32]
__global__ __launch_bounds__(256) void lora_xa_kernel(const float* __restrict__ A,
                                                      const float* __restrict__ la,
                                                      unsigned short* __restrict__ xah,
                                                      unsigned short* __restrict__ xal, int K) {
    const int m = blockIdx.x;
    const int tid = threadIdx.x;
    const int r = tid & 15, g = tid >> 4;
    float s = 0.f;
    const float* Am = A + (long)m * K;
    for (int k = g; k < K; k += 16) s += Am[k] * la[k * 16 + r];
    __shared__ float red[256];
    red[tid] = s; __syncthreads();
    for (int off = 128; off >= 16; off >>= 1) { if (tid < off) red[tid] += red[tid + off]; __syncthreads(); }
    if (tid < 16) {
        const float v = red[tid];
        const unsigned short h = f2bf(v);
        xah[m * 32 + tid] = h;
        xal[m * 32 + tid] = f2bf(v - bf2f(h));
    } else if (tid < 32) {
        xah[m * 32 + tid] = 0; xal[m * 32 + tid] = 0;
    }
}

// fp32 -> bf16 hi/lo split
__global__ void hilo_kernel(const float* __restrict__ in, unsigned short* __restrict__ hi,
                            unsigned short* __restrict__ lo, long n4) {
    const long i = (long)blockIdx.x * 256 + threadIdx.x;
    if (i >= n4) return;
    const float4 v = *(const float4*)(in + i * 4);
    ushort4 h, l;
    h.x = f2bf(v.x); l.x = f2bf(v.x - bf2f(h.x));
    h.y = f2bf(v.y); l.y = f2bf(v.y - bf2f(h.y));
    h.z = f2bf(v.z); l.z = f2bf(v.z - bf2f(h.z));
    h.w = f2bf(v.w); l.w = f2bf(v.w - bf2f(h.w));
    *(ushort4*)(hi + i * 4) = h;
    *(ushort4*)(lo + i * 4) = l;
}

// int32 weights (|w|<=127, exact in bf16) -> bf16
__global__ void w2bf_kernel(const int* __restrict__ wi, unsigned short* __restrict__ out, long n4) {
    const long i = (long)blockIdx.x * 256 + threadIdx.x;
    if (i >= n4) return;
    const int4 w = *(const int4*)(wi + i * 4);
    ushort4 o;
    o.x = (unsigned short)(__float_as_uint((float)w.x) >> 16);
    o.y = (unsigned short)(__float_as_uint((float)w.y) >> 16);
    o.z = (unsigned short)(__float_as_uint((float)w.z) >> 16);
    o.w = (unsigned short)(__float_as_uint((float)w.w) >> 16);
    *(ushort4*)(out + i * 4) = o;
}

// lbT[n][r] = lb[r][n] / sc[n] in bf16, padded to [N][32]
__global__ void lbt_kernel(const float* __restrict__ lb, const float* __restrict__ sc,
                           unsigned short* __restrict__ out, int N) {
    const int n = blockIdx.x * 256 + threadIdx.x;
    if (n >= N) return;
    const float inv = 1.0f / sc[n];
    for (int r = 0; r < 16; r++) out[n * 32 + r] = f2bf(lb[r * N + n] * inv);
    for (int r = 16; r < 32; r++) out[n * 32 + r] = 0;
}

__global__ void rope_kernel(float* __restrict__ x, const float* __restrict__ cs,
                            const float* __restrict__ sn, int nh) {
    const int idx = blockIdx.x * 256 + threadIdx.x;
    const int tot = 1024 * nh * 32;
    if (idx >= tot) return;
    const int d = idx & 31;
    const int h = (idx >> 5) % nh;
    const int s = (idx >> 5) / nh;
    float* p = x + s * (nh * 64) + h * 64;
    const float x1 = p[d], x2 = p[d + 32];
    const float c1 = cs[s * 64 + d],      s1 = sn[s * 64 + d];
    const float c2 = cs[s * 64 + d + 32], s2 = sn[s * 64 + d + 32];
    p[d]      = x1 * c1 - x2 * s1;
    p[d + 32] = x2 * c2 + x1 * s2;
}

__global__ void hadamard_kernel(const float* __restrict__ gate, const float* __restrict__ up,
                                float* __restrict__ had, int n) {
    const int i = blockIdx.x * 256 + threadIdx.x;
    if (i < n) {
        const float g = gate[i];
        const float fn = g / (1.f + expf(-g));
        had[i] = up[i] * fn;
    }
}

// ---------------- MFMA GEMM (m97-style: global_load_lds + dbuf + swizzle) ----------------
struct Seg {
    const unsigned short *W, *xh, *xl, *lbt;
    const float *sc, *b, *res;
    float *C;
    int N;
    int bx0;
};

__global__ __launch_bounds__(256) void gemm_mfma2_kernel(
    const unsigned short* __restrict__ Ah, const unsigned short* __restrict__ Al,
    int K, int c1, int c2, Seg s0, Seg s1, Seg s2)
{
    __shared__ unsigned short lds[2][3][4096];   // dbuf x {AH, AL, B} x 8KB = 48KB
    const int tid  = threadIdx.x;
    const int wave = tid >> 6, lane = tid & 63;
    const Seg s = (blockIdx.x < c1) ? s0 : (blockIdx.x < c2) ? s1 : s2;
    const int bn = (blockIdx.x - s.bx0) * 128;
    const int bm = blockIdx.y * 128;
    const int wm = (wave >> 1) * 64, wn = (wave & 1) * 64;
    const int l15 = lane & 15, l4 = lane >> 4;
    const int qe = ((l4 ^ ((l15 >> 1) & 3))) * 8;   // read-side swizzled chunk

    // loader lane constants: row-in-issue + swizzled source chunk
    const int lrow = lane >> 2;
    const int csrc = (lane & 3) ^ ((lane >> 3) & 3);
    const size_t strideMain = (size_t)K * 2;
    const int itersMain = K >> 5;

    floatx4 acc[4][4];
#pragma unroll
    for (int i = 0; i < 4; i++)
#pragma unroll
        for (int j = 0; j < 4; j++) acc[i][j] = (floatx4){0.f, 0.f, 0.f, 0.f};

    auto load3 = [&](int it, int buf) {
        const char *pAh, *pAl, *pB; size_t stA, stB, kb;
        if (it < itersMain) {
            pAh = (const char*)Ah; pAl = (const char*)Al; pB = (const char*)s.W;
            stA = strideMain; stB = strideMain; kb = (size_t)it * 64;
        } else {  // LoRA extra K-step
            pAh = (const char*)s.xh; pAl = (const char*)s.xl; pB = (const char*)s.lbt;
            stA = 64; stB = 64; kb = 0;
        }
#pragma unroll
        for (int issue = 0; issue < 2; issue++) {
            const int rt = wave * 32 + issue * 16 + lrow;
            const size_t co = kb + (size_t)csrc * 16;
            unsigned short* d0 = &lds[buf][0][(wave * 32 + issue * 16) * 32];
            unsigned short* d1 = &lds[buf][1][(wave * 32 + issue * 16) * 32];
            unsigned short* d2 = &lds[buf][2][(wave * 32 + issue * 16) * 32];
            gload_lds16(pAh + (size_t)(bm + rt) * stA + co, d0);
            gload_lds16(pAl + (size_t)(bm + rt) * stA + co, d1);
            gload_lds16(pB  + (size_t)(bn + rt) * stB + co, d2);
        }
    };

    load3(0, 0);
    for (int it = 0; it <= itersMain; it++) {
        const int cur = it & 1;
        __syncthreads();                       // buf[cur] loads done; prev reads done
        if (it < itersMain) load3(it + 1, cur ^ 1);
        const unsigned short* tAh = lds[cur][0];
        const unsigned short* tAl = lds[cur][1];
        const unsigned short* tB  = lds[cur][2];
        shortx8 afh[4], afl[4], bfr[4];
#pragma unroll
        for (int i = 0; i < 4; i++) {
            afh[i] = *(const shortx8*)&tAh[(wm + i * 16 + l15) * 32 + qe];
            afl[i] = *(const shortx8*)&tAl[(wm + i * 16 + l15) * 32 + qe];
            bfr[i] = *(const shortx8*)&tB [(wn + i * 16 + l15) * 32 + qe];
        }
#pragma unroll
        for (int i = 0; i < 4; i++)
#pragma unroll
            for (int j = 0; j < 4; j++) {
                acc[i][j] = __builtin_amdgcn_mfma_f32_16x16x32_bf16(afh[i], bfr[j], acc[i][j], 0, 0, 0);
                acc[i][j] = __builtin_amdgcn_mfma_f32_16x16x32_bf16(afl[i], bfr[j], acc[i][j], 0, 0, 0);
            }
    }

    // epilogue: D row = l4*4 + r, col = l15 within each 16x16 tile
#pragma unroll
    for (int j = 0; j < 4; j++) {
        const int n = bn + wn + j * 16 + l15;
        const float scn = s.sc[n], bsn = s.b[n];
#pragma unroll
        for (int i = 0; i < 4; i++) {
            const int m0 = bm + wm + i * 16 + l4 * 4;
#pragma unroll
            for (int r = 0; r < 4; r++) {
                const int m = m0 + r;
                float v = acc[i][j][r] * scn + bsn;
                if (s.res) v += s.res[(size_t)m * s.N + n];
                s.C[(size_t)m * s.N + n] = v;
            }
        }
    }
}

// ---------------- attention (fp32, tiled) ----------------
__global__ __launch_bounds__(256) void score_kernel(const float* __restrict__ q,
                                                    const float* __restrict__ kbuf,
                                                    float* __restrict__ probs) {
    const int bx = blockIdx.x, by = blockIdx.y, h = blockIdx.z;
    if (bx > by) return;
    __shared__ __align__(16) float Qs[16][68];
    __shared__ __align__(16) float Ks[16][68];
    const int tid = threadIdx.x;
    const int tx = tid & 15, ty = tid >> 4;
    const int lr = tid >> 2, lq = tid & 3;
    const float* Qp = q + (by * 64 + lr) * 2048 + h * 64 + lq * 4;
    const float* Kp = kbuf + (bx * 64 + lr) * 512 + (h >> 2) * 64 + lq * 4;
    float acc[4][4] = {};
    for (int k0 = 0; k0 < 64; k0 += 16) {
        const float4 av = *(const float4*)(Qp + k0);
        const float4 bv = *(const float4*)(Kp + k0);
        __syncthreads();
        Qs[lq*4+0][lr] = av.x; Qs[lq*4+1][lr] = av.y;
        Qs[lq*4+2][lr] = av.z; Qs[lq*4+3][lr] = av.w;
        Ks[lq*4+0][lr] = bv.x; Ks[lq*4+1][lr] = bv.y;
        Ks[lq*4+2][lr] = bv.z; Ks[lq*4+3][lr] = bv.w;
        __syncthreads();
#pragma unroll
        for (int kk = 0; kk < 16; kk++) {
            const float4 a4 = *(const float4*)&Qs[kk][ty * 4];
            const float4 b4 = *(const float4*)&Ks[kk][tx * 4];
            FMA16(a4, b4, acc);
        }
    }
#pragma unroll
    for (int i = 0; i < 4; i++) {
        float4 o;
        o.x = acc[i][0] * 0.125f; o.y = acc[i][1] * 0.125f;
        o.z = acc[i][2] * 0.125f; o.w = acc[i][3] * 0.125f;
        *(float4*)(probs + (long)((h * 1024) + by * 64 + ty * 4 + i) * 1024 + bx * 64 + tx * 4) = o;
    }
}

__global__ __launch_bounds__(256) void softmax_kernel(float* __restrict__ probs) {
    const int row = blockIdx.x;
    const int qi = row & 1023;
    float* p = probs + (long)row * 1024;
    const int tid = threadIdx.x;
    __shared__ float red[256];
    float m = -3.4e38f;
    for (int i = tid; i <= qi; i += 256) m = fmaxf(m, p[i]);
    red[tid] = m; __syncthreads();
    for (int off = 128; off; off >>= 1) { if (tid < off) red[tid] = fmaxf(red[tid], red[tid + off]); __syncthreads(); }
    m = red[0]; __syncthreads();
    float s = 0.f;
    for (int i = tid; i <= qi; i += 256) { float e = expf(p[i] - m); p[i] = e; s += e; }
    red[tid] = s; __syncthreads();
    for (int off = 128; off; off >>= 1) { if (tid < off) red[tid] += red[tid + off]; __syncthreads(); }
    const float inv = 1.f / red[0];
    for (int i = tid; i < 1024; i += 256) p[i] = (i <= qi) ? p[i] * inv : 0.f;
}

__global__ __launch_bounds__(256) void av_kernel(const float* __restrict__ probs,
                                                 const float* __restrict__ vbuf,
                                                 float* __restrict__ obuf) {
    const int by = blockIdx.x, h = blockIdx.y;
    __shared__ __align__(16) float Ps[16][68];
    __shared__ __align__(16) float Vs[16][64];
    const int tid = threadIdx.x;
    const int tx = tid & 15, ty = tid >> 4;
    const int lr = tid >> 2, lq = tid & 3;
    const int vk = tid >> 4, vd = tid & 15;
    const float* Pp = probs + (long)((h * 1024) + by * 64 + lr) * 1024 + lq * 4;
    const int kmax = (by + 1) * 64;
    float acc[4][4] = {};
    for (int k0 = 0; k0 < kmax; k0 += 16) {
        const float4 pv = *(const float4*)(Pp + k0);
        const float4 vv = *(const float4*)(vbuf + (k0 + vk) * 512 + (h >> 2) * 64 + vd * 4);
        __syncthreads();
        Ps[lq*4+0][lr] = pv.x; Ps[lq*4+1][lr] = pv.y;
        Ps[lq*4+2][lr] = pv.z; Ps[lq*4+3][lr] = pv.w;
        *(float4*)&Vs[vk][vd * 4] = vv;
        __syncthreads();
#pragma unroll
        for (int kk = 0; kk < 16; kk++) {
            const float4 a4 = *(const float4*)&Ps[kk][ty * 4];
            const float4 b4 = *(const float4*)&Vs[kk][tx * 4];
            FMA16(a4, b4, acc);
        }
    }
#pragma unroll
    for (int i = 0; i < 4; i++) {
        float4 o = make_float4(acc[i][0], acc[i][1], acc[i][2], acc[i][3]);
        *(float4*)(obuf + (by * 64 + ty * 4 + i) * 2048 + h * 64 + tx * 4) = o;
    }
}

// ---------------- exact quantile via radix select on float bits ----------------
__global__ void sel_init_kernel(unsigned* __restrict__ sel, unsigned* __restrict__ hist,
                                unsigned kA, unsigned kB) {
    const int i = blockIdx.x * 256 + threadIdx.x;
    if (i < 4096) hist[i] = 0u;
    if (i == 0) { sel[0] = 0u; sel[1] = kA; sel[2] = 0u; sel[3] = kB; }
}

__global__ __launch_bounds__(256) void hist_pass_kernel(const float* __restrict__ vals, long n,
                                                        const unsigned* __restrict__ sel,
                                                        unsigned* __restrict__ hist,
                                                        int shift, unsigned prefmask) {
    __shared__ unsigned h[4096];
    for (int i = threadIdx.x; i < 4096; i += 256) h[i] = 0u;
    __syncthreads();
    const unsigned prefix = sel[0];
    const long stride = (long)gridDim.x * 256;
    unsigned zcnt = 0;
    for (long i = (long)blockIdx.x * 256 + threadIdx.x; i < n; i += stride) {
        const unsigned b = __float_as_uint(vals[i]);
        if ((b & prefmask) == prefix) {
            if (b == 0u) zcnt++;
            else atomicAdd(&h[(b >> shift) & 4095], 1u);
        }
    }
    if (zcnt) atomicAdd(&h[0], zcnt);
    __syncthreads();
    for (int i = threadIdx.x; i < 4096; i += 256) if (h[i]) atomicAdd(&hist[i], h[i]);
}

__global__ __launch_bounds__(256) void resolve_pass_kernel(unsigned* __restrict__ sel,
                                                           unsigned* __restrict__ hist,
                                                           int shift, int last,
                                                           float* __restrict__ res, int slot,
                                                           int clear) {
    __shared__ unsigned part[256];
    __shared__ unsigned bpos, boff;
    const int tid = threadIdx.x;
    if (tid == 0) { bpos = 4095u; boff = 0u; }
    unsigned vals[16]; unsigned s = 0;
#pragma unroll
    for (int i = 0; i < 16; i++) { vals[i] = hist[tid * 16 + i]; s += vals[i]; }
    part[tid] = s; __syncthreads();
    for (int off = 1; off < 256; off <<= 1) {
        unsigned v = (tid >= off) ? part[tid - off] : 0u;
        __syncthreads();
        part[tid] += v;
        __syncthreads();
    }
    const unsigned krem = sel[1];
    unsigned c = part[tid] - s;
#pragma unroll
    for (int i = 0; i < 16; i++) {
        if (krem >= c && krem < c + vals[i]) { bpos = tid * 16 + i; boff = krem - c; }
        c += vals[i];
    }
    __syncthreads();
    if (tid == 0) {
        const unsigned p = sel[0] | (bpos << shift);
        sel[0] = p; sel[1] = boff;
        if (last) res[slot] = __uint_as_float(p);
    }
    if (clear) for (int i = 0; i < 16; i++) hist[tid * 16 + i] = 0u;
}

__global__ void finalize_thr_kernel(const float* __restrict__ res, float* __restrict__ out) {
    if (threadIdx.x == 0) out[0] = res[0] + (res[1] - res[0]) * 0.45f;
}

// ---------------- host side ----------------
extern "C" void kernel_launch(void* const* d_in, const int* in_sizes, int n_in,
                              void* d_out, int out_size, void* d_ws, size_t ws_size,
                              hipStream_t stream) {
    (void)in_sizes; (void)n_in; (void)out_size; (void)ws_size;
    const float* x    = (const float*)d_in[0];
    const float* w1   = (const float*)d_in[1];
    const float* w2   = (const float*)d_in[2];
    const float* cosp = (const float*)d_in[3];
    const float* sinp = (const float*)d_in[4];
    const int*   wi_q = (const int*)d_in[6];
    const float* sc_q = (const float*)d_in[7];
    const float* b_q  = (const float*)d_in[8];
    const float* la_q = (const float*)d_in[9];
    const float* lb_q = (const float*)d_in[10];
    const int*   wi_k = (const int*)d_in[11];
    const float* sc_k = (const float*)d_in[12];
    const float* b_k  = (const float*)d_in[13];
    const float* la_k = (const float*)d_in[14];
    const float* lb_k = (const float*)d_in[15];
    const int*   wi_v = (const int*)d_in[16];
    const float* sc_v = (const float*)d_in[17];
    const float* b_v  = (const float*)d_in[18];
    const float* la_v = (const float*)d_in[19];
    const float* lb_v = (const float*)d_in[20];
    const int*   wi_o = (const int*)d_in[21];
    const float* sc_o = (const float*)d_in[22];
    const float* b_o  = (const float*)d_in[23];
    const float* la_o = (const float*)d_in[24];
    const float* lb_o = (const float*)d_in[25];
    const int*   wi_g = (const int*)d_in[26];
    const float* sc_g = (const float*)d_in[27];
    const float* b_g  = (const float*)d_in[28];
    const float* la_g = (const float*)d_in[29];
    const float* lb_g = (const float*)d_in[30];
    const int*   wi_u = (const int*)d_in[31];
    const float* sc_u = (const float*)d_in[32];
    const float* b_u  = (const float*)d_in[33];
    const float* la_u = (const float*)d_in[34];
    const float* lb_u = (const float*)d_in[35];
    const int*   wi_d = (const int*)d_in[36];
    const float* sc_d = (const float*)d_in[37];
    const float* b_d  = (const float*)d_in[38];
    const float* la_d = (const float*)d_in[39];
    const float* lb_d = (const float*)d_in[40];

    float* F    = (float*)d_ws;
    float* XN1  = F + WS_XN1;
    float* Q    = F + WS_Q;
    float* K    = F + WS_KB;
    float* V    = F + WS_VB;
    float* O    = F + WS_OB;
    float* XMED = F + WS_XMED;
    float* XN2  = F + WS_XN2;
    float* PROBS= F + WS_PROBS;
    float* GATE = F + B_GATE;
    float* UP   = F + B_UP;
    float* HAD  = F + B_HAD;
    unsigned* CMX   = (unsigned*)(F + CM_X);
    unsigned* CMXN1 = (unsigned*)(F + CM_XN1);
    unsigned* CMQ   = (unsigned*)(F + CM_Qb);
    unsigned* CMK   = (unsigned*)(F + CM_Kb);
    unsigned* CMV   = (unsigned*)(F + CM_Vb);
    unsigned* CMO   = (unsigned*)(F + CM_Ob);
    unsigned* CMXM  = (unsigned*)(F + CM_XM);
    unsigned* CMXN2 = (unsigned*)(F + CM_XN2b);
    unsigned* CMG   = (unsigned*)(F + CM_GATE);
    unsigned* CMF   = (unsigned*)(F + CM_FN);
    unsigned* CMU   = (unsigned*)(F + CM_UPb);
    unsigned* CMH   = (unsigned*)(F + CM_HAD);
    int*      IDX0  = (int*)(F + WS_IDX);
    int*      IDX1  = IDX0 + 20;
    unsigned* HIST  = (unsigned*)(F + WS_HIST);
    unsigned* SEL   = (unsigned*)(F + WS_SEL);
    float*    RES   = F + WS_RES;
    float*    OUT   = (float*)d_out;
    #define US(off) ((unsigned short*)(F + (off)))

    // 0. zero column-max accumulators
    zero_kernel<<<(CM_TOTAL + 255) / 256, 256, 0, stream>>>(CMX, CM_TOTAL);

    // 1. rmsnorm1 + x channel pack + xn1 scale; convert W q/k/v -> bf16 (phase A)
    rmsnorm_kernel<<<1024, 256, 0, stream>>>(x, w1, XN1);
    colabsmax_kernel<<<dim3(8, 64), 256, 0, stream>>>(x, 1024, 2048, CMX, 0);
    topk20_kernel<<<1, 256, 0, stream>>>(CMX, OUT + O_XIDX, IDX0);
    packscale_kernel<<<8, 256, 0, stream>>>(CMX, IDX0, OUT + O_XSC, 2048);
    colabsmax_kernel<<<dim3(8, 64), 256, 0, stream>>>(XN1, 1024, 2048, CMXN1, 0);
    scale_fin_kernel<<<8, 256, 0, stream>>>(CMXN1, OUT + O_XN1S, 2048);
    w2bf_kernel<<<4096, 256, 0, stream>>>(wi_q, US(A_WQ), 1048576);
    w2bf_kernel<<<1024, 256, 0, stream>>>(wi_k, US(A_WK), 262144);
    w2bf_kernel<<<1024, 256, 0, stream>>>(wi_v, US(A_WV), 262144);

    // 2. q/k/v fused MFMA GEMM
    hilo_kernel<<<2048, 256, 0, stream>>>(XN1, US(A_XN1H), US(A_XN1L), 524288);
    lora_xa_kernel<<<1024, 256, 0, stream>>>(XN1, la_q, US(A_XAQH), US(A_XAQL), 2048);
    lora_xa_kernel<<<1024, 256, 0, stream>>>(XN1, la_k, US(A_XAKH), US(A_XAKL), 2048);
    lora_xa_kernel<<<1024, 256, 0, stream>>>(XN1, la_v, US(A_XAVH), US(A_XAVL), 2048);
    lbt_kernel<<<8, 256, 0, stream>>>(lb_q, sc_q, US(A_LBTQ), 2048);
    lbt_kernel<<<2, 256, 0, stream>>>(lb_k, sc_k, US(A_LBTK), 512);
    lbt_kernel<<<2, 256, 0, stream>>>(lb_v, sc_v, US(A_LBTV), 512);
    {
        Seg sq{US(A_WQ), US(A_XAQH), US(A_XAQL), US(A_LBTQ), sc_q, b_q, nullptr, Q, 2048, 0};
        Seg sk{US(A_WK), US(A_XAKH), US(A_XAKL), US(A_LBTK), sc_k, b_k, nullptr, K, 512, 16};
        Seg sv{US(A_WV), US(A_XAVH), US(A_XAVL), US(A_LBTV), sc_v, b_v, nullptr, V, 512, 20};
        gemm_mfma2_kernel<<<dim3(24, 8), 256, 0, stream>>>(US(A_XN1H), US(A_XN1L), 2048, 16, 20, sq, sk, sv);
    }

    // 3. rope + q/k/v scales
    rope_kernel<<<4096, 256, 0, stream>>>(Q, cosp, sinp, 32);
    rope_kernel<<<1024, 256, 0, stream>>>(K, cosp, sinp, 8);
    colabsmax_kernel<<<dim3(1, 256), 256, 0, stream>>>(Q, 32768, 64, CMQ, 0);
    scale_fin_kernel<<<1, 256, 0, stream>>>(CMQ, OUT + O_QS, 64);
    colabsmax_kernel<<<dim3(1, 128), 256, 0, stream>>>(K, 8192, 64, CMK, 0);
    scale_fin_kernel<<<1, 256, 0, stream>>>(CMK, OUT + O_KS, 64);
    colabsmax_kernel<<<dim3(1, 128), 256, 0, stream>>>(V, 8192, 64, CMV, 0);
    scale_fin_kernel<<<1, 256, 0, stream>>>(CMV, OUT + O_VS, 64);

    // 4. attention
    score_kernel<<<dim3(16, 16, 32), 256, 0, stream>>>(Q, K, PROBS);
    softmax_kernel<<<32768, 256, 0, stream>>>(PROBS);
    av_kernel<<<dim3(16, 32), 256, 0, stream>>>(PROBS, V, O);
    colabsmax_kernel<<<dim3(8, 64), 256, 0, stream>>>(O, 1024, 2048, CMO, 0);
    scale_fin_kernel<<<8, 256, 0, stream>>>(CMO, OUT + O_OS, 2048);

    // 5. a_thr: ranks 31876709/31876710 of 33554432, frac 0.45 (shared 1st pass)
    const long NP = 33554432L;
    sel_init_kernel<<<16, 256, 0, stream>>>(SEL, HIST, 31876709u, 31876710u);
    hist_pass_kernel<<<4096, 256, 0, stream>>>(PROBS, NP, SEL + 0, HIST, 20, 0x00000000u);
    resolve_pass_kernel<<<1, 256, 0, stream>>>(SEL + 0, HIST, 20, 0, RES, 0, 0);
    resolve_pass_kernel<<<1, 256, 0, stream>>>(SEL + 2, HIST, 20, 0, RES, 1, 1);
    hist_pass_kernel<<<4096, 256, 0, stream>>>(PROBS, NP, SEL + 0, HIST, 8, 0xFFF00000u);
    resolve_pass_kernel<<<1, 256, 0, stream>>>(SEL + 0, HIST, 8, 0, RES, 0, 1);
    hist_pass_kernel<<<4096, 256, 0, stream>>>(PROBS, NP, SEL + 2, HIST, 8, 0xFFF00000u);
    resolve_pass_kernel<<<1, 256, 0, stream>>>(SEL + 2, HIST, 8, 0, RES, 1, 1);
    hist_pass_kernel<<<4096, 256, 0, stream>>>(PROBS, NP, SEL + 0, HIST, 0, 0xFFFFFF00u);
    resolve_pass_kernel<<<1, 256, 0, stream>>>(SEL + 0, HIST, 0, 1, RES, 0, 1);
    hist_pass_kernel<<<4096, 256, 0, stream>>>(PROBS, NP, SEL + 2, HIST, 0, 0xFFFFFF00u);
    resolve_pass_kernel<<<1, 256, 0, stream>>>(SEL + 2, HIST, 0, 1, RES, 1, 1);
    finalize_thr_kernel<<<1, 64, 0, stream>>>(RES, OUT + O_ATHR);

    // 6. o projection (+residual x) -> x_med; pack; rmsnorm2  (phase B begins)
    w2bf_kernel<<<4096, 256, 0, stream>>>(wi_o, US(B_WO), 1048576);
    hilo_kernel<<<2048, 256, 0, stream>>>(O, US(B_OH), US(B_OL), 524288);
    lora_xa_kernel<<<1024, 256, 0, stream>>>(O, la_o, US(B_XAOH), US(B_XAOL), 2048);
    lbt_kernel<<<8, 256, 0, stream>>>(lb_o, sc_o, US(B_LBTO), 2048);
    {
        Seg so{US(B_WO), US(B_XAOH), US(B_XAOL), US(B_LBTO), sc_o, b_o, x, XMED, 2048, 0};
        gemm_mfma2_kernel<<<dim3(16, 8), 256, 0, stream>>>(US(B_OH), US(B_OL), 2048, 999, 999, so, so, so);
    }
    colabsmax_kernel<<<dim3(8, 64), 256, 0, stream>>>(XMED, 1024, 2048, CMXM, 0);
    topk20_kernel<<<1, 256, 0, stream>>>(CMXM, OUT + O_XMIDX, IDX1);
    packscale_kernel<<<8, 256, 0, stream>>>(CMXM, IDX1, OUT + O_XMS, 2048);
    rmsnorm_kernel<<<1024, 256, 0, stream>>>(XMED, w2, XN2);
    colabsmax_kernel<<<dim3(8, 64), 256, 0, stream>>>(XN2, 1024, 2048, CMXN2, 0);
    scale_fin_kernel<<<8, 256, 0, stream>>>(CMXN2, OUT + O_XN2S, 2048);

    // 7. MLP: gate+up fused GEMM
    w2bf_kernel<<<11264, 256, 0, stream>>>(wi_g, US(B_WG), 2883584);
    w2bf_kernel<<<11264, 256, 0, stream>>>(wi_u, US(B_WU), 2883584);
    hilo_kernel<<<2048, 256, 0, stream>>>(XN2, US(B_XN2H), US(B_XN2L), 524288);
    lora_xa_kernel<<<1024, 256, 0, stream>>>(XN2, la_g, US(B_XAGH), US(B_XAGL), 2048);
    lora_xa_kernel<<<1024, 256, 0, stream>>>(XN2, la_u, US(B_XAUH), US(B_XAUL), 2048);
    lbt_kernel<<<22, 256, 0, stream>>>(lb_g, sc_g, US(B_LBTG), 5632);
    lbt_kernel<<<22, 256, 0, stream>>>(lb_u, sc_u, US(B_LBTU), 5632);
    {
        Seg sg{US(B_WG), US(B_XAGH), US(B_XAGL), US(B_LBTG), sc_g, b_g, nullptr, GATE, 5632, 0};
        Seg su{US(B_WU), US(B_XAUH), US(B_XAUL), US(B_LBTU), sc_u, b_u, nullptr, UP, 5632, 44};
        gemm_mfma2_kernel<<<dim3(88, 8), 256, 0, stream>>>(US(B_XN2H), US(B_XN2L), 2048, 44, 88, sg, su, su);
    }
    w2bf_kernel<<<11264, 256, 0, stream>>>(wi_d, US(B_WD), 2883584);  // into dead WU slot
    colabsmax_kernel<<<dim3(22, 32), 256, 0, stream>>>(GATE, 1024, 5632, CMG, 0);
    scale_fin_kernel<<<22, 256, 0, stream>>>(CMG, OUT + O_GATES, 5632);
    colabsmax_kernel<<<dim3(22, 32), 256, 0, stream>>>(GATE, 1024, 5632, CMF, 1);
    scale_fin_kernel<<<22, 256, 0, stream>>>(CMF, OUT + O_FNS, 5632);
    colabsmax_kernel<<<dim3(22, 32), 256, 0, stream>>>(UP, 1024, 5632, CMU, 0);
    scale_fin_kernel<<<22, 256, 0, stream>>>(CMU, OUT + O_UPS, 5632);
    hadamard_kernel<<<22528, 256, 0, stream>>>(GATE, UP, HAD, 5767168);
    colabsmax_kernel<<<dim3(22, 32), 256, 0, stream>>>(HAD, 1024, 5632, CMH, 0);
    scale_fin_kernel<<<22, 256, 0, stream>>>(CMH, OUT + O_HADS, 5632);

    // 8. down projection (+residual x_med) -> x_out
    hilo_kernel<<<5632, 256, 0, stream>>>(HAD, US(B_HADH), US(B_HADL), 1441792);
    lora_xa_kernel<<<1024, 256, 0, stream>>>(HAD, la_d, US(B_XADH), US(B_XADL), 5632);
    lbt_kernel<<<8, 256, 0, stream>>>(lb_d, sc_d, US(B_LBTD), 2048);
    {
        Seg sd{US(B_WD), US(B_XADH), US(B_XADL), US(B_LBTD), sc_d, b_d, XMED, OUT + O_XOUT, 2048, 0};
        gemm_mfma2_kernel<<<dim3(16, 8), 256, 0, stream>>>(US(B_HADH), US(B_HADL), 5632, 999, 999, sd, sd, sd);
    }
    #undef US
}